// Round 11
// baseline (5665.081 us; speedup 1.0000x reference)
//
#include <hip/hip_runtime.h>
#include <hip/hip_bf16.h>
#include <math.h>

// ---- problem constants ----
#define V    32000
#define E    512
#define NH   8
#define DH   64
#define NL   2
#define FF   2048
#define MAXLEN 24
#define S    48
#define B    8
#define TRANS 14
#define INIT 12      // TRANS - 2
#define LF   35      // INIT + MAXLEN - 1

#define NB   256     // persistent grid blocks (1/CU, co-resident)
#define NT   1024    // threads per block (16 waves)

typedef float f4 __attribute__((ext_vector_type(4)));

__device__ inline float wsum(float v) {
#pragma unroll
  for (int off = 32; off; off >>= 1) v += __shfl_xor(v, off);
  return v;
}
__device__ inline float wmax(float v) {
#pragma unroll
  for (int off = 32; off; off >>= 1) v = fmaxf(v, __shfl_xor(v, off));
  return v;
}

// ---- write-through (relaxed agent) stores; readers use PLAIN cached loads of
// lines first-touched AFTER the write (rotated buffers; proven r5-r10) ----
__device__ inline void stc(float* p, float v) {
  __hip_atomic_store(p, v, __ATOMIC_RELAXED, __HIP_MEMORY_SCOPE_AGENT);
}
__device__ inline void stc8(float* p, float x, float y) {
  union { unsigned long long u; float f[2]; } c; c.f[0] = x; c.f[1] = y;
  __hip_atomic_store((unsigned long long*)p, c.u, __ATOMIC_RELAXED, __HIP_MEMORY_SCOPE_AGENT);
}
__device__ inline int ldci(const int* p) {
  return __hip_atomic_load(p, __ATOMIC_RELAXED, __HIP_MEMORY_SCOPE_AGENT);
}
__device__ inline void stci(int* p, int v) {
  __hip_atomic_store(p, v, __ATOMIC_RELAXED, __HIP_MEMORY_SCOPE_AGENT);
}

#define CMB(v, idx, ov, oi) do { if ((ov) > (v) || ((ov) == (v) && (oi) < (idx))) { (v) = (ov); (idx) = (oi); } } while (0)

// ================= prefill kernels (rounds 1-10, proven) =================

__global__ void embed_init_k(const int* __restrict__ transform, const float* __restrict__ emb,
                             float* __restrict__ xbuf) {
  int t = blockIdx.x;
  int pos = t >> 3, b = t & 7;
  int tok = transform[(1 + pos) * B + b];
  for (int d = threadIdx.x; d < E; d += blockDim.x) {
    double div = exp(-log(10000.0) * (double)(d & ~1) / (double)E);
    double ang = (double)pos * div;
    float pe = (d & 1) ? (float)cos(ang) : (float)sin(ang);
    xbuf[(size_t)t * E + d] = emb[(size_t)tok * E + d] + pe;
  }
}

template <int K>
__global__ __launch_bounds__(256) void gemm_k(
    const float* __restrict__ x, const float* __restrict__ W, const float* __restrict__ bias,
    int ntok, int nout, int route, int relu,
    float* __restrict__ out0, float* __restrict__ out1, float* __restrict__ out2) {
  constexpr int K4 = K / 4;
  constexpr int J  = K / 256;
  __shared__ float4 xt[8][K4];
  const int tid = threadIdx.x;
  const int lane = tid & 63;
  const int o = blockIdx.x * 4 + (tid >> 6);

  float4 wr[J];
  if (o < nout) {
    const float4* Wr = (const float4*)(W + (size_t)o * K);
#pragma unroll
    for (int j = 0; j < J; ++j) wr[j] = Wr[lane + 64 * j];
  }

  const int ng = ntok >> 3;
  for (int g = 0; g < ng; ++g) {
    if (g) __syncthreads();
    const float4* xg = (const float4*)(x + (size_t)g * 8 * K);
    float4* xf = &xt[0][0];
    for (int i = tid; i < 8 * K4; i += 256) xf[i] = xg[i];
    __syncthreads();
    if (o < nout) {
      float acc[8] = {0, 0, 0, 0, 0, 0, 0, 0};
#pragma unroll
      for (int j = 0; j < J; ++j) {
        float4 w = wr[j];
#pragma unroll
        for (int tt = 0; tt < 8; ++tt) {
          float4 xv = xt[tt][lane + 64 * j];
          acc[tt] += w.x * xv.x + w.y * xv.y + w.z * xv.z + w.w * xv.w;
        }
      }
#pragma unroll
      for (int tt = 0; tt < 8; ++tt) acc[tt] = wsum(acc[tt]);
      if (lane == 0) {
        float bo = bias[o];
#pragma unroll
        for (int tt = 0; tt < 8; ++tt) {
          float v = acc[tt] + bo;
          if (relu) v = fmaxf(v, 0.f);
          int t = g * 8 + tt;
          if (route == 0) {
            out0[(size_t)t * nout + o] = v;
          } else if (route == 1) {
            if (o < E) out0[(size_t)t * E + o] = v;
            else if (o < 2 * E) out1[(size_t)t * E + (o - E)] = v;
            else out2[(size_t)t * E + (o - 2 * E)] = v;
          } else {
            if (o < E) out0[(size_t)t * E + o] = v;
            else out1[(size_t)t * E + (o - E)] = v;
          }
        }
      }
    }
  }
}

__global__ __launch_bounds__(256) void attn_k(
    const float* __restrict__ q, const float* __restrict__ Kc, const float* __restrict__ Vc,
    float* __restrict__ outp, int p0, int nq, int nk_fixed, int causal) {
  const int tid = threadIdx.x;
  const int lane = tid & 63;
  const int u = blockIdx.x * 4 + (tid >> 6);
  if (u >= nq * 64) return;
  const int qi = u >> 6;
  const int r = u & 63;
  const int b = r >> 3, h = r & 7;
  const int nk = causal ? (p0 + qi + 1) : nk_fixed;

  const size_t qoff = (size_t)(qi * B + b) * E + h * DH + lane;
  const float qv = q[qoff];

  float myscore = -INFINITY;
  for (int k = 0; k < nk; ++k) {
    float prod = qv * Kc[(size_t)(k * B + b) * E + h * DH + lane];
    prod = wsum(prod);
    if (lane == k) myscore = prod * 0.125f;
  }
  float m = wmax(myscore);
  float p = (lane < nk) ? expf(myscore - m) : 0.f;
  float denom = wsum(p);
  float a = p / denom;

  float oacc = 0.f;
  for (int k = 0; k < nk; ++k) {
    float ak = __shfl(a, k);
    oacc = fmaf(ak, Vc[(size_t)(k * B + b) * E + h * DH + lane], oacc);
  }
  outp[qoff] = oacc;
}

__global__ __launch_bounds__(256) void add_ln_k(
    const float* __restrict__ xa, const float* __restrict__ xb,
    const float* __restrict__ g, const float* __restrict__ beta,
    float* __restrict__ outp, int ntok) {
  const int tid = threadIdx.x, lane = tid & 63;
  const int t = blockIdx.x * 4 + (tid >> 6);
  if (t >= ntok) return;
  float v[8];
  float s = 0.f;
#pragma unroll
  for (int j = 0; j < 8; ++j) {
    int d = lane + 64 * j;
    v[j] = xa[(size_t)t * E + d] + xb[(size_t)t * E + d];
    s += v[j];
  }
  s = wsum(s);
  float mean = s * (1.f / 512.f);
  float d2 = 0.f;
#pragma unroll
  for (int j = 0; j < 8; ++j) { float dd = v[j] - mean; d2 += dd * dd; }
  d2 = wsum(d2);
  float inv = 1.f / sqrtf(d2 * (1.f / 512.f) + 1e-5f);
#pragma unroll
  for (int j = 0; j < 8; ++j) {
    int d = lane + 64 * j;
    outp[(size_t)t * E + d] = (v[j] - mean) * inv * g[d] + beta[d];
  }
}

// ================= persistent decode v8: fused attn stages, 13 hops/step =================
// s_w: only row-distributed stage weights stay LDS-resident.
#define B_OW  0        // 2l x 2 rows x 512
#define B_COW 2048     // 2l x 2 rows x 512
#define B_FF1 4096     // 2l x 8 rows x 512
#define B_FF2 12288    // 4 rows x 2048 (layer = bid>>7)
#define SW_TOT 20480
#define SLOTS_PER_STEP 19
#define NSTAGE 13

__global__ __launch_bounds__(NT, 1) void decode_persist_k(
    const float* __restrict__ emb,
    const float* __restrict__ sa_w, const float* __restrict__ sa_b,
    const float* __restrict__ sa_ow, const float* __restrict__ sa_ob,
    const float* __restrict__ ca_w, const float* __restrict__ ca_b,
    const float* __restrict__ ca_ow, const float* __restrict__ ca_ob,
    const float* __restrict__ ff1_w, const float* __restrict__ ff1_b,
    const float* __restrict__ ff2_w, const float* __restrict__ ff2_b,
    const float* __restrict__ ln_g, const float* __restrict__ ln_b,
    const float* __restrict__ out_w, const float* __restrict__ out_b,
    float* __restrict__ kself, float* __restrict__ vself,
    const float* __restrict__ kcross, const float* __restrict__ vcross,
    float* __restrict__ arena, float* __restrict__ outp, int* __restrict__ bar) {
  __shared__ __align__(16) float s_w[SW_TOT];   // 80 KB weight slice
  __shared__ __align__(16) float s_x[8 * E];    // residual stream (persistent)
  __shared__ __align__(16) float s_raw[8 * E];  // staging
  __shared__ __align__(16) float s_qh[64];      // attn-block q
  __shared__ __align__(16) float s_kh[64];      // attn-block fresh k
  __shared__ __align__(16) float s_vh[64];      // attn-block fresh v
  __shared__ __align__(16) float s_attw[64];
  __shared__ __align__(16) float s_part[4][64];
  __shared__ float s_col[16];                   // proj collect (2 rows x 8 b)
  __shared__ float s_f1[8][8];                  // ff1 collect
  __shared__ float s_c2[8][4];                  // ff2 collect
  __shared__ int   s_tok[8];
  __shared__ float s_pv[16][8];
  __shared__ int   s_pi[16][8];
  __shared__ float s_rv[NT];
  __shared__ int   s_ri[NT];

  const int tid  = threadIdx.x;
  const int lane = tid & 63;
  const int wv   = tid >> 6;          // wave 0..15
  const int bid  = blockIdx.x;

  auto slot = [&](int st, int s) -> float* {
    return arena + ((size_t)st * SLOTS_PER_STEP + s) * 4096;
  };
  auto flg = [&](int s, int j) -> int* { return &bar[(s * 256 + j) * 16]; };

  auto set_flag = [&](int s, int tgt, bool producer) {
    __syncthreads();                  // all waves' stores drained (vmcnt 0)
    if (producer && tid == 0) stci(flg(s, bid), tgt);
  };
  auto wait_flags = [&](int s, int base, int count, int tgt) {
    if (wv == 0) {
      const int m = count - 1;
      for (;;) {
        bool ok = true;
        for (int f = lane; f < count; f += 64)
          ok &= (ldci(flg(s, base + ((f + bid) & m))) >= tgt);
        if (__all(ok)) break;
        __builtin_amdgcn_s_sleep(8);
      }
    }
    __syncthreads();
  };

  auto stage_raw = [&](const float* src) {
    const float4* s4 = (const float4*)src;
    float4* d4 = (float4*)s_raw;
    for (int k = tid; k < 1024; k += NT) d4[k] = s4[k];
    __syncthreads();
  };
  auto lnstage = [&](int lnidx) {
    if (wv < 8) {
      const float* gg = ln_g + (size_t)lnidx * E;
      const float* be = ln_b + (size_t)lnidx * E;
      float v[8]; float sum = 0.f;
#pragma unroll
      for (int j = 0; j < 8; ++j) {
        int d = lane + 64 * j;
        v[j] = s_x[wv * E + d] + s_raw[wv * E + d];
        sum += v[j];
      }
      sum = wsum(sum);
      float mean = sum * (1.f / 512.f);
      float d2 = 0.f;
#pragma unroll
      for (int j = 0; j < 8; ++j) { float dd = v[j] - mean; d2 += dd * dd; }
      d2 = wsum(d2);
      float inv = 1.f / sqrtf(d2 * (1.f / 512.f) + 1e-5f);
#pragma unroll
      for (int j = 0; j < 8; ++j) {
        int d = lane + 64 * j;
        s_x[wv * E + d] = (v[j] - mean) * inv * gg[d] + be[d];
      }
    }
    __syncthreads();
  };
  // 2 rows (bid*2+j) x 8 batches from s_raw; collected stc8 publish
  auto proj16v = [&](int wbase, const float* biasp, float* dst) {
    int j = wv & 1, b = wv >> 1;
    int r = bid * 2 + j;
    const f4* wp = (const f4*)&s_w[wbase + j * 512];
    f4 w0 = wp[lane], w1 = wp[lane + 64];
    const f4* x4 = (const f4*)(s_raw + b * E);
    f4 a = w0 * x4[lane] + w1 * x4[lane + 64];
    float acc = a.x + a.y + a.z + a.w;
    acc = wsum(acc);
    if (lane == 0) s_col[b * 2 + j] = acc + biasp[r];
    __syncthreads();
    if (tid < 8) stc8(&dst[tid * E + bid * 2], s_col[tid * 2], s_col[tid * 2 + 1]);
  };
  // shared attention core for block (b,h): q in s_qh; fresh k/v in s_kh/s_vh if self
  auto attn_core = [&](int b, int h, const float* Kbase, const float* Vbase,
                       int nk, int self, float* attdst) {
    if (wv == 0) {
      float sc = -INFINITY;
      if (lane < nk) {
        const f4* Kr = (self && lane == nk - 1) ? (const f4*)s_kh
                       : (const f4*)(Kbase + ((size_t)lane * B + b) * E + h * DH);
        const f4* Qp = (const f4*)s_qh;
        float a0 = 0.f;
#pragma unroll
        for (int u = 0; u < 16; ++u) {
          f4 kv = Kr[u], qq = Qp[u];
          a0 += kv.x * qq.x + kv.y * qq.y + kv.z * qq.z + kv.w * qq.w;
        }
        sc = a0 * 0.125f;
      }
      float m = wmax(sc);
      float e = (lane < nk) ? expf(sc - m) : 0.f;
      float den = wsum(e);
      s_attw[lane] = e / den;
    }
    __syncthreads();
    if (wv < 4) {
      float o = 0.f;
      for (int k = wv; k < nk; k += 4) {
        const float* vp = (self && k == nk - 1) ? s_vh
                          : &Vbase[((size_t)k * B + b) * E + h * DH];
        o = fmaf(s_attw[k], vp[lane], o);
      }
      s_part[wv][lane] = o;
    }
    __syncthreads();
    if (wv == 0) {
      float tot = s_part[0][lane] + s_part[1][lane] + s_part[2][lane] + s_part[3][lane];
      float lo = __shfl(tot, 2 * (lane & 31));
      float hi = __shfl(tot, 2 * (lane & 31) + 1);
      if (lane < 32) stc8(&attdst[b * E + h * DH + 2 * lane], lo, hi);
    }
  };

  // ================= one-time: preload weight slices into LDS =================
  {
    auto cprow = [&](const float* src, int dstf) {
      f4* d = (f4*)&s_w[dstf]; const f4* s = (const f4*)src;
      for (int k = tid; k < 128; k += NT) d[k] = s[k];
    };
    for (int l = 0; l < NL; ++l) {
      for (int j = 0; j < 2; ++j) {
        cprow(sa_ow + ((size_t)l * 512 + bid * 2 + j) * E, B_OW + (l * 2 + j) * 512);
        cprow(ca_ow + ((size_t)l * 512 + bid * 2 + j) * E, B_COW + (l * 2 + j) * 512);
      }
      for (int j = 0; j < 8; ++j)
        cprow(ff1_w + ((size_t)l * FF + bid * 8 + j) * E, B_FF1 + (l * 8 + j) * 512);
    }
    const int lf2 = bid >> 7;
    for (int j = 0; j < 4; ++j) {
      f4* d = (f4*)&s_w[B_FF2 + j * 2048];
      const f4* s = (const f4*)(ff2_w + ((size_t)lf2 * 512 + (bid & 127) * 4 + j) * FF);
      for (int k = tid; k < 512; k += NT) d[k] = s[k];
    }
    __syncthreads();
  }

  // ================= 23 autoregressive steps =================
  for (int i = 0; i < MAXLEN - 1; ++i) {
    const int p = INIT + i;
    const int tgt = i + 1;
    float* amax_o = slot(i, 0);

    // ---- wait prev step's argmax partials; token select + embed (redundant) ----
    if (i > 0) wait_flags(12, 0, 256, i);
    {
      int bw = wv & 7;
      float v = -INFINITY; int ix = 0x7fffffff;
      if (i == 0) {
        const float2* row = (const float2*)(outp + ((size_t)(INIT - 1) * B + bw) * V);
        for (int jj = lane; jj < V / 2; jj += 64) {
          float2 t = row[jj];
          CMB(v, ix, t.x, 2 * jj);
          CMB(v, ix, t.y, 2 * jj + 1);
        }
      } else {
        const float2* ap = (const float2*)slot(i - 1, 0);
#pragma unroll
        for (int t = 0; t < 4; ++t) {
          int e = lane * 4 + t;
          float2 pr = ap[e * 8 + bw];
          CMB(v, ix, pr.x, (int)pr.y);
        }
      }
#pragma unroll
      for (int off = 1; off < 64; off <<= 1) {
        float ov = __shfl_xor(v, off); int oi = __shfl_xor(ix, off);
        CMB(v, ix, ov, oi);
      }
      if (lane == 0 && wv < 8) s_tok[bw] = ix;
      __syncthreads();
      int b = tid >> 7, d0 = (tid & 127) * 4;
      int tok = s_tok[b];
      float4 ev = *(const float4*)(emb + (size_t)tok * E + d0);
      s_x[b * E + d0]     = ev.x;          // pe[0]: even +0
      s_x[b * E + d0 + 1] = ev.y + 1.0f;   // odd  +1
      s_x[b * E + d0 + 2] = ev.z;
      s_x[b * E + d0 + 3] = ev.w + 1.0f;
      __syncthreads();
    }

    for (int l = 0; l < NL; ++l) {
      const int sb = l * 6;
      float* Lb    = slot(i, 1 + l * 9);
      float* att_s = Lb;
      float* raw_s = Lb + 4096;
      float* att_c = Lb + 8192;
      float* raw_c = Lb + 12288;
      float* hb    = Lb + 16384;         // [8][2048] (4 slots)
      float* yb    = Lb + 32768;

      // ---- A: self-attention incl. own QKV (blocks 0..63: b=bid>>3, h=bid&7) ----
      if (bid < 64) {
        const int b = bid >> 3, h = bid & 7;
        // QKV rows for (head h, batch b): 192 rows over 16 waves
#pragma unroll
        for (int t = 0; t < 12; ++t) {
          int idx = wv * 12 + t;
          int sec = idx >> 6, o = idx & 63;
          const f4* wp = (const f4*)(sa_w + ((size_t)l * 1536 + sec * 512 + h * 64 + o) * E);
          const f4* x4 = (const f4*)&s_x[b * E];
          f4 a = wp[lane] * x4[lane] + wp[lane + 64] * x4[lane + 64];
          float acc = a.x + a.y + a.z + a.w;
          acc = wsum(acc);
          if (lane == 0) {
            acc += sa_b[(size_t)l * 1536 + sec * 512 + h * 64 + o];
            if (sec == 0) s_qh[o] = acc;
            else if (sec == 1) s_kh[o] = acc;
            else s_vh[o] = acc;
          }
        }
        __syncthreads();
        // fresh k,v -> cache (plain; self-consumed by this block in later steps)
        if (tid < 16)
          ((float4*)(kself + ((size_t)(l * LF + p) * B + b) * E + h * DH))[tid] =
              ((float4*)s_kh)[tid];
        else if (tid < 32)
          ((float4*)(vself + ((size_t)(l * LF + p) * B + b) * E + h * DH))[tid - 16] =
              ((float4*)s_vh)[tid - 16];
        attn_core(b, h, kself + (size_t)l * LF * B * E, vself + (size_t)l * LF * B * E,
                  p + 1, 1, att_s);
      }
      set_flag(sb + 0, tgt, bid < 64);
      wait_flags(sb + 0, 0, 64, tgt);
      // ---- B: self out-proj ----
      stage_raw(att_s);
      proj16v(B_OW + l * 1024, sa_ob + (size_t)l * E, raw_s);
      set_flag(sb + 1, tgt, true);
      wait_flags(sb + 1, 0, 256, tgt);
      // ---- C: x1 = LN(x + raw); cross-attn incl. own q_c ----
      stage_raw(raw_s);
      lnstage(l * 3 + 0);
      if (bid < 64) {
        const int b = bid >> 3, h = bid & 7;
#pragma unroll
        for (int t = 0; t < 4; ++t) {
          int o = wv * 4 + t;
          const f4* wp = (const f4*)(ca_w + ((size_t)l * 1536 + h * 64 + o) * E);
          const f4* x4 = (const f4*)&s_x[b * E];
          f4 a = wp[lane] * x4[lane] + wp[lane + 64] * x4[lane + 64];
          float acc = a.x + a.y + a.z + a.w;
          acc = wsum(acc);
          if (lane == 0) s_qh[o] = acc + ca_b[(size_t)l * 1536 + h * 64 + o];
        }
        __syncthreads();
        attn_core(b, h, kcross + (size_t)l * S * B * E, vcross + (size_t)l * S * B * E,
                  S, 0, att_c);
      }
      set_flag(sb + 2, tgt, bid < 64);
      wait_flags(sb + 2, 0, 64, tgt);
      // ---- D: cross out-proj ----
      stage_raw(att_c);
      proj16v(B_COW + l * 1024, ca_ob + (size_t)l * E, raw_c);
      set_flag(sb + 3, tgt, true);
      wait_flags(sb + 3, 0, 256, tgt);
      // ---- E: x2 = LN(x1 + raw); ff1 (relu), collected publish ----
      stage_raw(raw_c);
      lnstage(l * 3 + 1);
      {
        int j = wv >> 1, bg = (wv & 1) * 4;
        int r = bid * 8 + j;
        const f4* wp = (const f4*)&s_w[B_FF1 + (l * 8 + j) * 512];
        f4 w0 = wp[lane], w1 = wp[lane + 64];
        float bias = ff1_b[(size_t)l * FF + r];
        for (int b = bg; b < bg + 4; ++b) {
          const f4* x4 = (const f4*)&s_x[b * E];
          f4 a = w0 * x4[lane] + w1 * x4[lane + 64];
          float acc = a.x + a.y + a.z + a.w;
          acc = wsum(acc);
          if (lane == 0) s_f1[b][j] = fmaxf(acc + bias, 0.f);
        }
      }
      __syncthreads();
      if (tid < 32) {
        int b = tid >> 2, q = tid & 3;
        stc8(&hb[b * FF + bid * 8 + q * 2], s_f1[b][q * 2], s_f1[b][q * 2 + 1]);
      }
      set_flag(sb + 4, tgt, true);
      wait_flags(sb + 4, 0, 256, tgt);
      // ---- F: ff2 (producers: bid>>7 == l; rows (bid&127)*4..+3, K=2048) ----
      if ((bid >> 7) == l) {
        int b = wv >> 1, j0 = (wv & 1) * 2;
        int r0 = (bid & 127) * 4;
        const f4* h4 = (const f4*)(hb + b * FF);
        f4 hv[8];
#pragma unroll
        for (int j = 0; j < 8; ++j) hv[j] = h4[j * 64 + lane];
#pragma unroll
        for (int jr = 0; jr < 2; ++jr) {
          int rl = j0 + jr;
          const f4* wp = (const f4*)&s_w[B_FF2 + rl * 2048];
          float acc = 0.f;
#pragma unroll
          for (int j = 0; j < 8; ++j) {
            f4 w = wp[j * 64 + lane];
            acc += w.x * hv[j].x + w.y * hv[j].y + w.z * hv[j].z + w.w * hv[j].w;
          }
          acc = wsum(acc);
          if (lane == 0) s_c2[b][rl] = acc + ff2_b[(size_t)l * 512 + r0 + rl];
        }
        __syncthreads();
        if (tid < 16) {
          int b2 = tid >> 1, q = tid & 1;
          stc8(&yb[b2 * E + r0 + q * 2], s_c2[b2][q * 2], s_c2[b2][q * 2 + 1]);
        }
      }
      set_flag(sb + 5, tgt, (bid >> 7) == l);
      wait_flags(sb + 5, l * 128, 128, tgt);
      // ---- G: x3/next-input = LN(x2 + y) (local, no flag) ----
      stage_raw(yb);
      lnstage(l * 3 + 2);
    }

    // ---- logits (125 rows/block, cached out_w, PLAIN stores) + partial argmax ----
    {
      const int grp = lane >> 3, sub = lane & 7;
      const int idx = wv * 8 + grp;            // 0..127
      const bool valid = idx < 125;
      const int r = bid * 125 + idx;
      float acc[8] = {0, 0, 0, 0, 0, 0, 0, 0};
      if (valid) {
        const f4* wrow = (const f4*)(out_w + (size_t)r * E);
#pragma unroll
        for (int half = 0; half < 2; ++half) {
          f4 w8[8];
#pragma unroll
          for (int j = 0; j < 8; ++j) w8[j] = wrow[(half * 8 + j) * 8 + sub];
#pragma unroll
          for (int b = 0; b < 8; ++b) {
            const f4* x4 = (const f4*)&s_x[b * E];
            float a = 0.f;
#pragma unroll
            for (int j = 0; j < 8; ++j) {
              f4 xx = x4[(half * 8 + j) * 8 + sub];
              a += w8[j].x * xx.x + w8[j].y * xx.y + w8[j].z * xx.z + w8[j].w * xx.w;
            }
            acc[b] += a;
          }
        }
#pragma unroll
        for (int b = 0; b < 8; ++b) {
          acc[b] += __shfl_xor(acc[b], 1);
          acc[b] += __shfl_xor(acc[b], 2);
          acc[b] += __shfl_xor(acc[b], 4);
        }
        if (sub == 0) {
          float bo = out_b[r];
#pragma unroll
          for (int b = 0; b < 8; ++b) {
            acc[b] += bo;
            outp[((size_t)p * B + b) * V + r] = acc[b];   // host-only reader
          }
        }
      }
#pragma unroll
      for (int b = 0; b < 8; ++b) {
        float v = (valid && sub == 0) ? acc[b] : -INFINITY;
        int ix = (valid && sub == 0) ? r : 0x7fffffff;
#pragma unroll
        for (int off = 1; off < 64; off <<= 1) {
          float ov = __shfl_xor(v, off); int oi = __shfl_xor(ix, off);
          CMB(v, ix, ov, oi);
        }
        if (lane == 0) { s_pv[wv][b] = v; s_pi[wv][b] = ix; }
      }
      __syncthreads();
      if (wv == 0) {
        int b = lane & 7, w2 = lane >> 3;
        float v = s_pv[w2][b]; int ix = s_pi[w2][b];
        float v2 = s_pv[w2 + 8][b]; int ix2 = s_pi[w2 + 8][b];
        CMB(v, ix, v2, ix2);
#pragma unroll
        for (int off = 8; off < 64; off <<= 1) {
          float ov = __shfl_xor(v, off); int oi = __shfl_xor(ix, off);
          CMB(v, ix, ov, oi);
        }
        if (lane < 8) stc8(&amax_o[(size_t)(bid * 8 + lane) * 2], v, (float)ix);
      }
    }
    set_flag(12, tgt, true);       // consumed at top of next step
  }
}

extern "C" void kernel_launch(void* const* d_in, const int* in_sizes, int n_in,
                              void* d_out, int out_size, void* d_ws, size_t ws_size,
                              hipStream_t stream) {
  const float* enc       = (const float*)d_in[0];
  const int*   transform = (const int*)d_in[1];
  const float* emb       = (const float*)d_in[3];
  const float* sa_w  = (const float*)d_in[4];
  const float* sa_b  = (const float*)d_in[5];
  const float* sa_ow = (const float*)d_in[6];
  const float* sa_ob = (const float*)d_in[7];
  const float* ca_w  = (const float*)d_in[8];
  const float* ca_b  = (const float*)d_in[9];
  const float* ca_ow = (const float*)d_in[10];
  const float* ca_ob = (const float*)d_in[11];
  const float* ff1_w = (const float*)d_in[12];
  const float* ff1_b = (const float*)d_in[13];
  const float* ff2_w = (const float*)d_in[14];
  const float* ff2_b = (const float*)d_in[15];
  const float* ln_g  = (const float*)d_in[16];
  const float* ln_b  = (const float*)d_in[17];
  const float* out_w = (const float*)d_in[18];
  const float* out_b = (const float*)d_in[19];
  float* out = (float*)d_out;

  // workspace layout (floats)
  const size_t SELF_SZ  = (size_t)LF * B * E;    // 143360
  const size_t CROSS_SZ = (size_t)S * B * E;     // 196608
  const size_t ARENA_SZ = (size_t)(MAXLEN - 1) * SLOTS_PER_STEP * 4096;  // 7.1 MB
  const size_t FLAG_SZ  = (size_t)NSTAGE * 256 * 16;                     // ints
  float* ws     = (float*)d_ws;
  float* xbuf   = ws;                            // prefill embeddings [12*B, E]
  float* kself  = xbuf + (size_t)INIT * B * E;
  float* vself  = kself + NL * SELF_SZ;
  float* kcross = vself + NL * SELF_SZ;
  float* vcross = kcross + NL * CROSS_SZ;
  float* arena  = vcross + NL * CROSS_SZ;
  int*   bar    = (int*)(arena + ARENA_SZ);
  float* act1   = (float*)(bar + FLAG_SZ);
  float* act2   = act1 + 96 * E;
  float* act3   = act2 + 96 * E;
  float* ffb    = act3 + 96 * E;                 // [96,FF]

  hipMemsetAsync(bar, 0, FLAG_SZ * 4, stream);

  // 1) initial embeddings (positions 0..11)
  embed_init_k<<<INIT * B, 128, 0, stream>>>(transform, emb, xbuf);

  // 2) cross-attn K/V caches
  for (int l = 0; l < NL; ++l) {
    gemm_k<E><<<(2 * E) / 4, 256, 0, stream>>>(
        enc, ca_w + ((size_t)l * 3 * E + E) * E, ca_b + (size_t)l * 3 * E + E,
        S * B, 2 * E, 2, 0, kcross + l * CROSS_SZ, vcross + l * CROSS_SZ, nullptr);
  }

  // 3) prefill positions 0..11 (multi-kernel, one-time)
  {
    const int p0 = 0, nq = INIT, ntok = nq * B;
    const float* xin = xbuf;
    for (int l = 0; l < NL; ++l) {
      const float* x = (l == 0) ? xin : act1;
      gemm_k<E><<<(3 * E) / 4, 256, 0, stream>>>(
          x, sa_w + (size_t)l * 3 * E * E, sa_b + (size_t)l * 3 * E, ntok, 3 * E, 1, 0,
          act2, kself + l * SELF_SZ, vself + l * SELF_SZ);
      attn_k<<<nq * 16, 256, 0, stream>>>(act2, kself + l * SELF_SZ, vself + l * SELF_SZ,
                                          act3, p0, nq, 0, 1);
      gemm_k<E><<<E / 4, 256, 0, stream>>>(
          act3, sa_ow + (size_t)l * E * E, sa_ob + (size_t)l * E, ntok, E, 0, 0, act2, nullptr, nullptr);
      add_ln_k<<<(ntok + 3) / 4, 256, 0, stream>>>(
          x, act2, ln_g + (size_t)l * 3 * E, ln_b + (size_t)l * 3 * E, act1, ntok);
      gemm_k<E><<<E / 4, 256, 0, stream>>>(
          act1, ca_w + (size_t)l * 3 * E * E, ca_b + (size_t)l * 3 * E, ntok, E, 0, 0, act2, nullptr, nullptr);
      attn_k<<<nq * 16, 256, 0, stream>>>(act2, kcross + l * CROSS_SZ, vcross + l * CROSS_SZ,
                                          act3, p0, nq, S, 0);
      gemm_k<E><<<E / 4, 256, 0, stream>>>(
          act3, ca_ow + (size_t)l * E * E, ca_ob + (size_t)l * E, ntok, E, 0, 0, act2, nullptr, nullptr);
      add_ln_k<<<(ntok + 3) / 4, 256, 0, stream>>>(
          act1, act2, ln_g + (size_t)l * 3 * E + E, ln_b + (size_t)l * 3 * E + E, act1, ntok);
      gemm_k<E><<<FF / 4, 256, 0, stream>>>(
          act1, ff1_w + (size_t)l * FF * E, ff1_b + (size_t)l * FF, ntok, FF, 0, 1, ffb, nullptr, nullptr);
      gemm_k<FF><<<E / 4, 256, 0, stream>>>(
          ffb, ff2_w + (size_t)l * E * FF, ff2_b + (size_t)l * E, ntok, E, 0, 0, act2, nullptr, nullptr);
      add_ln_k<<<(ntok + 3) / 4, 256, 0, stream>>>(
          act1, act2, ln_g + (size_t)l * 3 * E + 2 * E, ln_b + (size_t)l * 3 * E + 2 * E, act1, ntok);
    }
    gemm_k<E><<<V / 4, 256, 0, stream>>>(
        act1, out_w, out_b, ntok, V, 0, 0, out, nullptr, nullptr);
  }

  // 4) persistent kernel: all 23 autoregressive steps
  decode_persist_k<<<NB, NT, 0, stream>>>(
      emb, sa_w, sa_b, sa_ow, sa_ob, ca_w, ca_b, ca_ow, ca_ob,
      ff1_w, ff1_b, ff2_w, ff2_b, ln_g, ln_b, out_w, out_b,
      kself, vself, kcross, vcross, arena, out, bar);
}

// Round 12
// 5251.023 us; speedup vs baseline: 1.0789x; 1.0789x over previous
//
#include <hip/hip_runtime.h>
#include <hip/hip_bf16.h>
#include <math.h>

// ---- problem constants ----
#define V    32000
#define E    512
#define NH   8
#define DH   64
#define NL   2
#define FF   2048
#define MAXLEN 24
#define S    48
#define B    8
#define TRANS 14
#define INIT 12      // TRANS - 2
#define LF   35      // INIT + MAXLEN - 1

#define NB   256     // persistent grid blocks (1/CU, co-resident)
#define NT   1024    // threads per block (16 waves)

typedef float f4 __attribute__((ext_vector_type(4)));

__device__ inline float wsum(float v) {
#pragma unroll
  for (int off = 32; off; off >>= 1) v += __shfl_xor(v, off);
  return v;
}
__device__ inline float wmax(float v) {
#pragma unroll
  for (int off = 32; off; off >>= 1) v = fmaxf(v, __shfl_xor(v, off));
  return v;
}

// ---- write-through (relaxed agent) stores; readers use PLAIN cached loads of
// lines first-touched AFTER the write (rotated buffers; proven r5-r10) ----
__device__ inline void stc(float* p, float v) {
  __hip_atomic_store(p, v, __ATOMIC_RELAXED, __HIP_MEMORY_SCOPE_AGENT);
}
__device__ inline void stc8(float* p, float x, float y) {
  union { unsigned long long u; float f[2]; } c; c.f[0] = x; c.f[1] = y;
  __hip_atomic_store((unsigned long long*)p, c.u, __ATOMIC_RELAXED, __HIP_MEMORY_SCOPE_AGENT);
}
__device__ inline int ldci(const int* p) {
  return __hip_atomic_load(p, __ATOMIC_RELAXED, __HIP_MEMORY_SCOPE_AGENT);
}
__device__ inline void stci(int* p, int v) {
  __hip_atomic_store(p, v, __ATOMIC_RELAXED, __HIP_MEMORY_SCOPE_AGENT);
}

#define CMB(v, idx, ov, oi) do { if ((ov) > (v) || ((ov) == (v) && (oi) < (idx))) { (v) = (ov); (idx) = (oi); } } while (0)

// ================= prefill kernels =================

__global__ void embed_init_k(const int* __restrict__ transform, const float* __restrict__ emb,
                             float* __restrict__ xbuf) {
  int t = blockIdx.x;
  int pos = t >> 3, b = t & 7;
  int tok = transform[(1 + pos) * B + b];
  for (int d = threadIdx.x; d < E; d += blockDim.x) {
    double div = exp(-log(10000.0) * (double)(d & ~1) / (double)E);
    double ang = (double)pos * div;
    float pe = (d & 1) ? (float)cos(ang) : (float)sin(ang);
    xbuf[(size_t)t * E + d] = emb[(size_t)tok * E + d] + pe;
  }
}

// 16 rows/block (1024 threads, wave-per-row). Same lane-indexed dot and wsum
// order as the 4-row gemm_k -> bit-identical results; 4x less panel re-staging.
template <int K>
__global__ __launch_bounds__(1024) void gemm16_k(
    const float* __restrict__ x, const float* __restrict__ W, const float* __restrict__ bias,
    int ntok, int nout, int route, int relu,
    float* __restrict__ out0, float* __restrict__ out1, float* __restrict__ out2) {
  constexpr int K4 = K / 4;
  constexpr int J  = K / 256;
  __shared__ float4 xt[8][K4];
  const int tid = threadIdx.x;
  const int lane = tid & 63;
  const int o = blockIdx.x * 16 + (tid >> 6);

  float4 wr[J];
  if (o < nout) {
    const float4* Wr = (const float4*)(W + (size_t)o * K);
#pragma unroll
    for (int j = 0; j < J; ++j) wr[j] = Wr[lane + 64 * j];
  }

  const int ng = ntok >> 3;
  for (int g = 0; g < ng; ++g) {
    if (g) __syncthreads();
    const float4* xg = (const float4*)(x + (size_t)g * 8 * K);
    float4* xf = &xt[0][0];
    for (int i = tid; i < 8 * K4; i += 1024) xf[i] = xg[i];
    __syncthreads();
    if (o < nout) {
      float acc[8] = {0, 0, 0, 0, 0, 0, 0, 0};
#pragma unroll
      for (int j = 0; j < J; ++j) {
        float4 w = wr[j];
#pragma unroll
        for (int tt = 0; tt < 8; ++tt) {
          float4 xv = xt[tt][lane + 64 * j];
          acc[tt] += w.x * xv.x + w.y * xv.y + w.z * xv.z + w.w * xv.w;
        }
      }
#pragma unroll
      for (int tt = 0; tt < 8; ++tt) acc[tt] = wsum(acc[tt]);
      if (lane == 0) {
        float bo = bias[o];
#pragma unroll
        for (int tt = 0; tt < 8; ++tt) {
          float v = acc[tt] + bo;
          if (relu) v = fmaxf(v, 0.f);
          int t = g * 8 + tt;
          if (route == 0) {
            out0[(size_t)t * nout + o] = v;
          } else if (route == 1) {
            if (o < E) out0[(size_t)t * E + o] = v;
            else if (o < 2 * E) out1[(size_t)t * E + (o - E)] = v;
            else out2[(size_t)t * E + (o - 2 * E)] = v;
          } else {
            if (o < E) out0[(size_t)t * E + o] = v;
            else out1[(size_t)t * E + (o - E)] = v;
          }
        }
      }
    }
  }
}

__global__ __launch_bounds__(256) void attn_k(
    const float* __restrict__ q, const float* __restrict__ Kc, const float* __restrict__ Vc,
    float* __restrict__ outp, int p0, int nq, int nk_fixed, int causal) {
  const int tid = threadIdx.x;
  const int lane = tid & 63;
  const int u = blockIdx.x * 4 + (tid >> 6);
  if (u >= nq * 64) return;
  const int qi = u >> 6;
  const int r = u & 63;
  const int b = r >> 3, h = r & 7;
  const int nk = causal ? (p0 + qi + 1) : nk_fixed;

  const size_t qoff = (size_t)(qi * B + b) * E + h * DH + lane;
  const float qv = q[qoff];

  float myscore = -INFINITY;
  for (int k = 0; k < nk; ++k) {
    float prod = qv * Kc[(size_t)(k * B + b) * E + h * DH + lane];
    prod = wsum(prod);
    if (lane == k) myscore = prod * 0.125f;
  }
  float m = wmax(myscore);
  float p = (lane < nk) ? expf(myscore - m) : 0.f;
  float denom = wsum(p);
  float a = p / denom;

  float oacc = 0.f;
  for (int k = 0; k < nk; ++k) {
    float ak = __shfl(a, k);
    oacc = fmaf(ak, Vc[(size_t)(k * B + b) * E + h * DH + lane], oacc);
  }
  outp[qoff] = oacc;
}

__global__ __launch_bounds__(256) void add_ln_k(
    const float* __restrict__ xa, const float* __restrict__ xb,
    const float* __restrict__ g, const float* __restrict__ beta,
    float* __restrict__ outp, int ntok) {
  const int tid = threadIdx.x, lane = tid & 63;
  const int t = blockIdx.x * 4 + (tid >> 6);
  if (t >= ntok) return;
  float v[8];
  float s = 0.f;
#pragma unroll
  for (int j = 0; j < 8; ++j) {
    int d = lane + 64 * j;
    v[j] = xa[(size_t)t * E + d] + xb[(size_t)t * E + d];
    s += v[j];
  }
  s = wsum(s);
  float mean = s * (1.f / 512.f);
  float d2 = 0.f;
#pragma unroll
  for (int j = 0; j < 8; ++j) { float dd = v[j] - mean; d2 += dd * dd; }
  d2 = wsum(d2);
  float inv = 1.f / sqrtf(d2 * (1.f / 512.f) + 1e-5f);
#pragma unroll
  for (int j = 0; j < 8; ++j) {
    int d = lane + 64 * j;
    outp[(size_t)t * E + d] = (v[j] - mean) * inv * g[d] + beta[d];
  }
}

// ================= persistent decode v6 (round-10, proven 3.89 ms) =================
#define B_QKV 0        // 2l x 6 rows x 512
#define B_OW  6144     // 2l x 2 rows x 512
#define B_CQ  8192     // 2l x 2 rows x 512
#define B_COW 10240    // 2l x 2 rows x 512
#define B_FF1 12288    // 2l x 8 rows x 512
#define B_FF2 20480    // 4 rows x 2048 (layer = bid>>7)
#define SW_TOT 28672
#define SLOTS_PER_STEP 23
#define NSTAGE 17

__global__ __launch_bounds__(NT, 1) void decode_persist_k(
    const float* __restrict__ emb,
    const float* __restrict__ sa_w, const float* __restrict__ sa_b,
    const float* __restrict__ sa_ow, const float* __restrict__ sa_ob,
    const float* __restrict__ ca_w, const float* __restrict__ ca_b,
    const float* __restrict__ ca_ow, const float* __restrict__ ca_ob,
    const float* __restrict__ ff1_w, const float* __restrict__ ff1_b,
    const float* __restrict__ ff2_w, const float* __restrict__ ff2_b,
    const float* __restrict__ ln_g, const float* __restrict__ ln_b,
    const float* __restrict__ out_w, const float* __restrict__ out_b,
    float* __restrict__ kself, float* __restrict__ vself,
    const float* __restrict__ kcross, const float* __restrict__ vcross,
    float* __restrict__ arena, float* __restrict__ outp, int* __restrict__ bar) {
  __shared__ __align__(16) float s_w[SW_TOT];   // 112 KB weight slice
  __shared__ __align__(16) float s_x[8 * E];    // residual stream (persistent)
  __shared__ __align__(16) float s_raw[8 * E];  // staging
  __shared__ __align__(16) float s_q2[64];
  __shared__ __align__(16) float s_attw[64];
  __shared__ __align__(16) float s_part[4][64];
  __shared__ int   s_tok[8];
  __shared__ float s_pv[16][8];
  __shared__ int   s_pi[16][8];

  const int tid  = threadIdx.x;
  const int lane = tid & 63;
  const int wv   = tid >> 6;          // wave 0..15
  const int bid  = blockIdx.x;
  int gen = 0;

  auto slot = [&](int st, int s) -> float* {
    return arena + ((size_t)st * SLOTS_PER_STEP + s) * 4096;
  };
  auto flg = [&](int s, int j) -> int* { return &bar[(s * 256 + j) * 16]; };

  auto set_flag = [&](int s, int tgt, bool producer) {
    __syncthreads();
    if (producer && tid == 0) stci(flg(s, bid), tgt);
  };
  auto wait_flags = [&](int s, int base, int count, int tgt) {
    if (wv == 0) {
      const int m = count - 1;
      for (;;) {
        bool ok = true;
        for (int f = lane; f < count; f += 64)
          ok &= (ldci(flg(s, base + ((f + bid) & m))) >= tgt);
        if (__all(ok)) break;
        __builtin_amdgcn_s_sleep(12);
      }
    }
    __syncthreads();
  };

  auto stage_raw = [&](const float* src) {
    const float4* s4 = (const float4*)src;
    float4* d4 = (float4*)s_raw;
    for (int k = tid; k < 1024; k += NT) d4[k] = s4[k];
    __syncthreads();
  };
  auto lnstage = [&](int lnidx) {
    if (wv < 8) {
      const float* gg = ln_g + (size_t)lnidx * E;
      const float* be = ln_b + (size_t)lnidx * E;
      float v[8]; float sum = 0.f;
#pragma unroll
      for (int j = 0; j < 8; ++j) {
        int d = lane + 64 * j;
        v[j] = s_x[wv * E + d] + s_raw[wv * E + d];
        sum += v[j];
      }
      sum = wsum(sum);
      float mean = sum * (1.f / 512.f);
      float d2 = 0.f;
#pragma unroll
      for (int j = 0; j < 8; ++j) { float dd = v[j] - mean; d2 += dd * dd; }
      d2 = wsum(d2);
      float inv = 1.f / sqrtf(d2 * (1.f / 512.f) + 1e-5f);
#pragma unroll
      for (int j = 0; j < 8; ++j) {
        int d = lane + 64 * j;
        s_x[wv * E + d] = (v[j] - mean) * inv * gg[d] + be[d];
      }
    }
    __syncthreads();
  };
  auto proj16 = [&](int wbase, const float* srcLDS, const float* biasp, float* dst) {
    int j = wv & 1, b = wv >> 1;
    int r = bid * 2 + j;
    const f4* wp = (const f4*)&s_w[wbase + j * 512];
    f4 w0 = wp[lane], w1 = wp[lane + 64];
    const f4* x4 = (const f4*)(srcLDS + b * E);
    f4 a = w0 * x4[lane] + w1 * x4[lane + 64];
    float acc = a.x + a.y + a.z + a.w;
    acc = wsum(acc);
    if (lane == 0) stc(&dst[b * E + r], acc + biasp[r]);
  };
  auto attn_stage = [&](const float* qsrc, const float* Kbase, const float* Vbase,
                        int nk, float* attdst) {
    const int b = bid >> 3, h = bid & 7;
    if (wv == 0) {
      s_q2[lane] = qsrc[b * E + h * DH + lane];
      float sc = -INFINITY;
      if (lane < nk) {
        const f4* Kr = (const f4*)(Kbase + ((size_t)lane * B + b) * E + h * DH);
        const f4* Qp = (const f4*)s_q2;
        float a0 = 0.f;
#pragma unroll
        for (int u = 0; u < 16; ++u) {
          f4 kv = Kr[u], qq = Qp[u];
          a0 += kv.x * qq.x + kv.y * qq.y + kv.z * qq.z + kv.w * qq.w;
        }
        sc = a0 * 0.125f;
      }
      float m = wmax(sc);
      float e = (lane < nk) ? expf(sc - m) : 0.f;
      float den = wsum(e);
      s_attw[lane] = e / den;
    }
    __syncthreads();
    if (wv < 4) {
      float o = 0.f;
      for (int k = wv; k < nk; k += 4)
        o = fmaf(s_attw[k], Vbase[((size_t)k * B + b) * E + h * DH + lane], o);
      s_part[wv][lane] = o;
    }
    __syncthreads();
    if (wv == 0)
      stc(&attdst[b * E + h * DH + lane],
          s_part[0][lane] + s_part[1][lane] + s_part[2][lane] + s_part[3][lane]);
  };

  // ---- one-time: preload weight slices into LDS ----
  {
    auto cprow = [&](const float* src, int dstf) {
      f4* d = (f4*)&s_w[dstf]; const f4* s = (const f4*)src;
      for (int k = tid; k < 128; k += NT) d[k] = s[k];
    };
    for (int l = 0; l < NL; ++l) {
      for (int j = 0; j < 6; ++j)
        cprow(sa_w + ((size_t)l * 1536 + bid * 6 + j) * E, B_QKV + (l * 6 + j) * 512);
      for (int j = 0; j < 2; ++j) {
        cprow(sa_ow + ((size_t)l * 512 + bid * 2 + j) * E, B_OW + (l * 2 + j) * 512);
        cprow(ca_w + ((size_t)l * 1536 + bid * 2 + j) * E, B_CQ + (l * 2 + j) * 512);
        cprow(ca_ow + ((size_t)l * 512 + bid * 2 + j) * E, B_COW + (l * 2 + j) * 512);
      }
      for (int j = 0; j < 8; ++j)
        cprow(ff1_w + ((size_t)l * FF + bid * 8 + j) * E, B_FF1 + (l * 8 + j) * 512);
    }
    const int lf2 = bid >> 7;
    for (int j = 0; j < 4; ++j) {
      f4* d = (f4*)&s_w[B_FF2 + j * 2048];
      const f4* s = (const f4*)(ff2_w + ((size_t)lf2 * 512 + (bid & 127) * 4 + j) * FF);
      for (int k = tid; k < 512; k += NT) d[k] = s[k];
    }
    __syncthreads();
  }

  // ---- 23 autoregressive steps ----
  for (int i = 0; i < MAXLEN - 1; ++i) {
    const int p = INIT + i;
    const int tgt = i + 1;
    float* amax_o = slot(i, 0);

    if (i > 0) wait_flags(16, 0, 256, i);
    {
      int bw = wv & 7;
      float v = -INFINITY; int ix = 0x7fffffff;
      if (i == 0) {
        const float2* row = (const float2*)(outp + ((size_t)(INIT - 1) * B + bw) * V);
        for (int jj = lane; jj < V / 2; jj += 64) {
          float2 t = row[jj];
          CMB(v, ix, t.x, 2 * jj);
          CMB(v, ix, t.y, 2 * jj + 1);
        }
      } else {
        const float2* ap = (const float2*)slot(i - 1, 0);
#pragma unroll
        for (int t = 0; t < 4; ++t) {
          int e = lane * 4 + t;
          float2 pr = ap[e * 8 + bw];
          CMB(v, ix, pr.x, (int)pr.y);
        }
      }
#pragma unroll
      for (int off = 1; off < 64; off <<= 1) {
        float ov = __shfl_xor(v, off); int oi = __shfl_xor(ix, off);
        CMB(v, ix, ov, oi);
      }
      if (lane == 0 && wv < 8) s_tok[bw] = ix;
      __syncthreads();
      int b = tid >> 7, d0 = (tid & 127) * 4;
      int tok = s_tok[b];
      float4 ev = *(const float4*)(emb + (size_t)tok * E + d0);
      s_x[b * E + d0]     = ev.x;
      s_x[b * E + d0 + 1] = ev.y + 1.0f;
      s_x[b * E + d0 + 2] = ev.z;
      s_x[b * E + d0 + 3] = ev.w + 1.0f;
      __syncthreads();
    }

    for (int l = 0; l < NL; ++l) {
      const int sb = l * 8;
      float* Lb    = slot(i, 1 + l * 11);
      float* q_s   = Lb;
      float* att_s = Lb + 4096;
      float* raw_s = Lb + 8192;
      float* q_c   = Lb + 12288;
      float* att_c = Lb + 16384;
      float* raw_c = Lb + 20480;
      float* hb    = Lb + 24576;
      float* yb    = Lb + 40960;

      if (wv < 12) {
        int j = wv >> 1, bg = (wv & 1) * 4;
        int r = bid * 6 + j, sec = r >> 9, off = r & 511;
        const f4* wp = (const f4*)&s_w[B_QKV + (l * 6 + j) * 512];
        f4 w0 = wp[lane], w1 = wp[lane + 64];
        float bias = sa_b[(size_t)l * 1536 + r];
        for (int b = bg; b < bg + 4; ++b) {
          const f4* x4 = (const f4*)&s_x[b * E];
          f4 a = w0 * x4[lane] + w1 * x4[lane + 64];
          float acc = a.x + a.y + a.z + a.w;
          acc = wsum(acc);
          if (lane == 0) {
            acc += bias;
            if (sec == 0) stc(&q_s[b * E + off], acc);
            else if (sec == 1) stc(&kself[((size_t)(l * LF + p) * B + b) * E + off], acc);
            else stc(&vself[((size_t)(l * LF + p) * B + b) * E + off], acc);
          }
        }
      }
      set_flag(sb + 0, tgt, true);
      wait_flags(sb + 0, 0, 256, tgt);
      if (bid < 64)
        attn_stage(q_s, kself + (size_t)l * LF * B * E, vself + (size_t)l * LF * B * E,
                   p + 1, att_s);
      set_flag(sb + 1, tgt, bid < 64);
      wait_flags(sb + 1, 0, 64, tgt);
      stage_raw(att_s);
      proj16(B_OW + l * 1024, s_raw, sa_ob + (size_t)l * E, raw_s);
      set_flag(sb + 2, tgt, true);
      wait_flags(sb + 2, 0, 256, tgt);
      stage_raw(raw_s);
      lnstage(l * 3 + 0);
      proj16(B_CQ + l * 1024, s_x, ca_b + (size_t)l * 3 * E, q_c);
      set_flag(sb + 3, tgt, true);
      wait_flags(sb + 3, 0, 256, tgt);
      if (bid < 64)
        attn_stage(q_c, kcross + (size_t)l * S * B * E, vcross + (size_t)l * S * B * E,
                   S, att_c);
      set_flag(sb + 4, tgt, bid < 64);
      wait_flags(sb + 4, 0, 64, tgt);
      stage_raw(att_c);
      proj16(B_COW + l * 1024, s_raw, ca_ob + (size_t)l * E, raw_c);
      set_flag(sb + 5, tgt, true);
      wait_flags(sb + 5, 0, 256, tgt);
      stage_raw(raw_c);
      lnstage(l * 3 + 1);
      {
        int j = wv >> 1, bg = (wv & 1) * 4;
        int r = bid * 8 + j;
        const f4* wp = (const f4*)&s_w[B_FF1 + (l * 8 + j) * 512];
        f4 w0 = wp[lane], w1 = wp[lane + 64];
        float bias = ff1_b[(size_t)l * FF + r];
        for (int b = bg; b < bg + 4; ++b) {
          const f4* x4 = (const f4*)&s_x[b * E];
          f4 a = w0 * x4[lane] + w1 * x4[lane + 64];
          float acc = a.x + a.y + a.z + a.w;
          acc = wsum(acc);
          if (lane == 0) stc(&hb[b * FF + r], fmaxf(acc + bias, 0.f));
        }
      }
      set_flag(sb + 6, tgt, true);
      wait_flags(sb + 6, 0, 256, tgt);
      if ((bid >> 7) == l) {
        int b = wv >> 1, j0 = (wv & 1) * 2;
        int r0 = (bid & 127) * 4;
        const f4* h4 = (const f4*)(hb + b * FF);
        f4 hv[8];
#pragma unroll
        for (int j = 0; j < 8; ++j) hv[j] = h4[j * 64 + lane];
#pragma unroll
        for (int jr = 0; jr < 2; ++jr) {
          int rl = j0 + jr;
          const f4* wp = (const f4*)&s_w[B_FF2 + rl * 2048];
          float acc = 0.f;
#pragma unroll
          for (int j = 0; j < 8; ++j) {
            f4 w = wp[j * 64 + lane];
            acc += w.x * hv[j].x + w.y * hv[j].y + w.z * hv[j].z + w.w * hv[j].w;
          }
          acc = wsum(acc);
          if (lane == 0)
            stc(&yb[b * E + r0 + rl], acc + ff2_b[(size_t)l * 512 + r0 + rl]);
        }
      }
      set_flag(sb + 7, tgt, (bid >> 7) == l);
      wait_flags(sb + 7, l * 128, 128, tgt);
      stage_raw(yb);
      lnstage(l * 3 + 2);
    }

    {
      const int grp = lane >> 3, sub = lane & 7;
      const int idx = wv * 8 + grp;
      const bool valid = idx < 125;
      const int r = bid * 125 + idx;
      float acc[8] = {0, 0, 0, 0, 0, 0, 0, 0};
      if (valid) {
        const f4* wrow = (const f4*)(out_w + (size_t)r * E);
#pragma unroll
        for (int half = 0; half < 2; ++half) {
          f4 w8[8];
#pragma unroll
          for (int j = 0; j < 8; ++j) w8[j] = wrow[(half * 8 + j) * 8 + sub];
#pragma unroll
          for (int b = 0; b < 8; ++b) {
            const f4* x4 = (const f4*)&s_x[b * E];
            float a = 0.f;
#pragma unroll
            for (int j = 0; j < 8; ++j) {
              f4 xx = x4[(half * 8 + j) * 8 + sub];
              a += w8[j].x * xx.x + w8[j].y * xx.y + w8[j].z * xx.z + w8[j].w * xx.w;
            }
            acc[b] += a;
          }
        }
#pragma unroll
        for (int b = 0; b < 8; ++b) {
          acc[b] += __shfl_xor(acc[b], 1);
          acc[b] += __shfl_xor(acc[b], 2);
          acc[b] += __shfl_xor(acc[b], 4);
        }
        if (sub == 0) {
          float bo = out_b[r];
#pragma unroll
          for (int b = 0; b < 8; ++b) {
            acc[b] += bo;
            outp[((size_t)p * B + b) * V + r] = acc[b];
          }
        }
      }
#pragma unroll
      for (int b = 0; b < 8; ++b) {
        float v = (valid && sub == 0) ? acc[b] : -INFINITY;
        int ix = (valid && sub == 0) ? r : 0x7fffffff;
#pragma unroll
        for (int off = 1; off < 64; off <<= 1) {
          float ov = __shfl_xor(v, off); int oi = __shfl_xor(ix, off);
          CMB(v, ix, ov, oi);
        }
        if (lane == 0) { s_pv[wv][b] = v; s_pi[wv][b] = ix; }
      }
      __syncthreads();
      if (wv == 0) {
        int b = lane & 7, w2 = lane >> 3;
        float v = s_pv[w2][b]; int ix = s_pi[w2][b];
        float v2 = s_pv[w2 + 8][b]; int ix2 = s_pi[w2 + 8][b];
        CMB(v, ix, v2, ix2);
#pragma unroll
        for (int off = 8; off < 64; off <<= 1) {
          float ov = __shfl_xor(v, off); int oi = __shfl_xor(ix, off);
          CMB(v, ix, ov, oi);
        }
        if (lane < 8) stc8(&amax_o[(size_t)(bid * 8 + lane) * 2], v, (float)ix);
      }
    }
    set_flag(16, tgt, true);
  }
}

extern "C" void kernel_launch(void* const* d_in, const int* in_sizes, int n_in,
                              void* d_out, int out_size, void* d_ws, size_t ws_size,
                              hipStream_t stream) {
  const float* enc       = (const float*)d_in[0];
  const int*   transform = (const int*)d_in[1];
  const float* emb       = (const float*)d_in[3];
  const float* sa_w  = (const float*)d_in[4];
  const float* sa_b  = (const float*)d_in[5];
  const float* sa_ow = (const float*)d_in[6];
  const float* sa_ob = (const float*)d_in[7];
  const float* ca_w  = (const float*)d_in[8];
  const float* ca_b  = (const float*)d_in[9];
  const float* ca_ow = (const float*)d_in[10];
  const float* ca_ob = (const float*)d_in[11];
  const float* ff1_w = (const float*)d_in[12];
  const float* ff1_b = (const float*)d_in[13];
  const float* ff2_w = (const float*)d_in[14];
  const float* ff2_b = (const float*)d_in[15];
  const float* ln_g  = (const float*)d_in[16];
  const float* ln_b  = (const float*)d_in[17];
  const float* out_w = (const float*)d_in[18];
  const float* out_b = (const float*)d_in[19];
  float* out = (float*)d_out;

  // workspace layout (floats)
  const size_t SELF_SZ  = (size_t)LF * B * E;
  const size_t CROSS_SZ = (size_t)S * B * E;
  const size_t ARENA_SZ = (size_t)(MAXLEN - 1) * SLOTS_PER_STEP * 4096;
  const size_t FLAG_SZ  = (size_t)NSTAGE * 256 * 16;
  float* ws     = (float*)d_ws;
  float* xbuf   = ws;
  float* kself  = xbuf + (size_t)INIT * B * E;
  float* vself  = kself + NL * SELF_SZ;
  float* kcross = vself + NL * SELF_SZ;
  float* vcross = kcross + NL * CROSS_SZ;
  float* arena  = vcross + NL * CROSS_SZ;
  int*   bar    = (int*)(arena + ARENA_SZ);
  float* act1   = (float*)(bar + FLAG_SZ);
  float* act2   = act1 + 96 * E;
  float* act3   = act2 + 96 * E;
  float* ffb    = act3 + 96 * E;

  hipMemsetAsync(bar, 0, FLAG_SZ * 4, stream);

  // 1) initial embeddings (positions 0..11)
  embed_init_k<<<INIT * B, 128, 0, stream>>>(transform, emb, xbuf);

  // 2) cross-attn K/V caches (16-row blocks: 4x less panel re-staging)
  for (int l = 0; l < NL; ++l) {
    gemm16_k<E><<<(2 * E) / 16, 1024, 0, stream>>>(
        enc, ca_w + ((size_t)l * 3 * E + E) * E, ca_b + (size_t)l * 3 * E + E,
        S * B, 2 * E, 2, 0, kcross + l * CROSS_SZ, vcross + l * CROSS_SZ, nullptr);
  }

  // 3) prefill positions 0..11 (multi-kernel, one-time)
  {
    const int p0 = 0, nq = INIT, ntok = nq * B;
    const float* xin = xbuf;
    for (int l = 0; l < NL; ++l) {
      const float* x = (l == 0) ? xin : act1;
      gemm16_k<E><<<(3 * E) / 16, 1024, 0, stream>>>(
          x, sa_w + (size_t)l * 3 * E * E, sa_b + (size_t)l * 3 * E, ntok, 3 * E, 1, 0,
          act2, kself + l * SELF_SZ, vself + l * SELF_SZ);
      attn_k<<<nq * 16, 256, 0, stream>>>(act2, kself + l * SELF_SZ, vself + l * SELF_SZ,
                                          act3, p0, nq, 0, 1);
      gemm16_k<E><<<E / 16, 1024, 0, stream>>>(
          act3, sa_ow + (size_t)l * E * E, sa_ob + (size_t)l * E, ntok, E, 0, 0, act2, nullptr, nullptr);
      add_ln_k<<<(ntok + 3) / 4, 256, 0, stream>>>(
          x, act2, ln_g + (size_t)l * 3 * E, ln_b + (size_t)l * 3 * E, act1, ntok);
      gemm16_k<E><<<E / 16, 1024, 0, stream>>>(
          act1, ca_w + (size_t)l * 3 * E * E, ca_b + (size_t)l * 3 * E, ntok, E, 0, 0, act2, nullptr, nullptr);
      attn_k<<<nq * 16, 256, 0, stream>>>(act2, kcross + l * CROSS_SZ, vcross + l * CROSS_SZ,
                                          act3, p0, nq, S, 0);
      gemm16_k<E><<<E / 16, 1024, 0, stream>>>(
          act3, ca_ow + (size_t)l * E * E, ca_ob + (size_t)l * E, ntok, E, 0, 0, act2, nullptr, nullptr);
      add_ln_k<<<(ntok + 3) / 4, 256, 0, stream>>>(
          act1, act2, ln_g + (size_t)l * 3 * E + E, ln_b + (size_t)l * 3 * E + E, act1, ntok);
      gemm16_k<E><<<FF / 16, 1024, 0, stream>>>(
          act1, ff1_w + (size_t)l * FF * E, ff1_b + (size_t)l * FF, ntok, FF, 0, 1, ffb, nullptr, nullptr);
      gemm16_k<FF><<<E / 16, 1024, 0, stream>>>(
          ffb, ff2_w + (size_t)l * E * FF, ff2_b + (size_t)l * E, ntok, E, 0, 0, act2, nullptr, nullptr);
      add_ln_k<<<(ntok + 3) / 4, 256, 0, stream>>>(
          act1, act2, ln_g + (size_t)l * 3 * E + 2 * E, ln_b + (size_t)l * 3 * E + 2 * E, act1, ntok);
    }
    gemm16_k<E><<<V / 16, 1024, 0, stream>>>(
        act1, out_w, out_b, ntok, V, 0, 0, out, nullptr, nullptr);
  }

  // 4) persistent kernel: all 23 autoregressive steps (r10, unchanged)
  decode_persist_k<<<NB, NT, 0, stream>>>(
      emb, sa_w, sa_b, sa_ow, sa_ob, ca_w, ca_b, ca_ow, ca_ob,
      ff1_w, ff1_b, ff2_w, ff2_b, ln_g, ln_b, out_w, out_b,
      kself, vself, kcross, vcross, arena, out, bar);
}

// Round 13
// 4631.282 us; speedup vs baseline: 1.2232x; 1.1338x over previous
//
#include <hip/hip_runtime.h>
#include <hip/hip_bf16.h>
#include <math.h>

// ---- problem constants ----
#define V    32000
#define E    512
#define NH   8
#define DH   64
#define NL   2
#define FF   2048
#define MAXLEN 24
#define S    48
#define B    8
#define TRANS 14
#define INIT 12      // TRANS - 2
#define LF   35      // INIT + MAXLEN - 1

#define NB   256
#define NT   1024

typedef float f4 __attribute__((ext_vector_type(4)));

__device__ inline float wsum(float v) {
#pragma unroll
  for (int off = 32; off; off >>= 1) v += __shfl_xor(v, off);
  return v;
}
__device__ inline float wmax(float v) {
#pragma unroll
  for (int off = 32; off; off >>= 1) v = fmaxf(v, __shfl_xor(v, off));
  return v;
}

__device__ inline void stc(float* p, float v) {
  __hip_atomic_store(p, v, __ATOMIC_RELAXED, __HIP_MEMORY_SCOPE_AGENT);
}
__device__ inline void stc8(float* p, float x, float y) {
  union { unsigned long long u; float f[2]; } c; c.f[0] = x; c.f[1] = y;
  __hip_atomic_store((unsigned long long*)p, c.u, __ATOMIC_RELAXED, __HIP_MEMORY_SCOPE_AGENT);
}
__device__ inline int ldci(const int* p) {
  return __hip_atomic_load(p, __ATOMIC_RELAXED, __HIP_MEMORY_SCOPE_AGENT);
}
__device__ inline void stci(int* p, int v) {
  __hip_atomic_store(p, v, __ATOMIC_RELAXED, __HIP_MEMORY_SCOPE_AGENT);
}

#define CMB(v, idx, ov, oi) do { if ((ov) > (v) || ((ov) == (v) && (oi) < (idx))) { (v) = (ov); (idx) = (oi); } } while (0)

// ---- initial token embeddings (positions 0..11), separate dispatch ----
__global__ void embed_init_k(const int* __restrict__ transform, const float* __restrict__ emb,
                             float* __restrict__ xbuf) {
  int t = blockIdx.x;
  int pos = t >> 3, b = t & 7;
  int tok = transform[(1 + pos) * B + b];
  for (int d = threadIdx.x; d < E; d += blockDim.x) {
    double div = exp(-log(10000.0) * (double)(d & ~1) / (double)E);
    double ang = (double)pos * div;
    float pe = (d & 1) ? (float)cos(ang) : (float)sin(ang);
    xbuf[(size_t)t * E + d] = emb[(size_t)tok * E + d] + pe;
  }
}

// ================= persistent kernel: prefill + 23 decode steps =================
#define B_QKV 0
#define B_OW  6144
#define B_CQ  8192
#define B_COW 10240
#define B_FF1 12288
#define B_FF2 20480
#define SW_TOT 28672
#define SLOTS_PER_STEP 23
#define NSTAGE 41          // 0..16 decode, 17..38 prefill layers, 39 crossKV, 40 prelogits

#define PRE_L   688128     // floats per prefill layer block
#define PQ_OFF  0
#define PATTS   49152
#define PRAWS   98304
#define PX1     147456
#define PQC     196608
#define PATTC   245760
#define PRAWC   294912
#define PX2     344064
#define PY      393216
#define PX3     442368
#define PHB     491520

__global__ __launch_bounds__(NT, 1) void decode_persist_k(
    const float* __restrict__ enc, const float* __restrict__ emb,
    const float* __restrict__ sa_w, const float* __restrict__ sa_b,
    const float* __restrict__ sa_ow, const float* __restrict__ sa_ob,
    const float* __restrict__ ca_w, const float* __restrict__ ca_b,
    const float* __restrict__ ca_ow, const float* __restrict__ ca_ob,
    const float* __restrict__ ff1_w, const float* __restrict__ ff1_b,
    const float* __restrict__ ff2_w, const float* __restrict__ ff2_b,
    const float* __restrict__ ln_g, const float* __restrict__ ln_b,
    const float* __restrict__ out_w, const float* __restrict__ out_b,
    const float* __restrict__ xpre, float* __restrict__ pre, float* __restrict__ amax_pre,
    float* __restrict__ kself, float* __restrict__ vself,
    float* __restrict__ kcross, float* __restrict__ vcross,
    float* __restrict__ arena, float* __restrict__ outp, int* __restrict__ bar) {
  __shared__ __align__(16) float s_w[SW_TOT];   // 112 KB (prefill: scratch; decode: weights)
  __shared__ __align__(16) float s_x[8 * E];
  __shared__ __align__(16) float s_raw[8 * E];
  __shared__ __align__(16) float s_q2[64];
  __shared__ __align__(16) float s_attw[64];
  __shared__ __align__(16) float s_part[4][64];
  __shared__ int   s_tok[8];
  __shared__ float s_pv[16][8];
  __shared__ int   s_pi[16][8];

  const int tid  = threadIdx.x;
  const int lane = tid & 63;
  const int wv   = tid >> 6;
  const int bid  = blockIdx.x;
  const size_t CROSS_SZ = (size_t)S * B * E;

  auto slot = [&](int st, int s) -> float* {
    return arena + ((size_t)st * SLOTS_PER_STEP + s) * 4096;
  };
  auto flg = [&](int s, int j) -> int* { return &bar[(s * 256 + j) * 16]; };
  auto set_flag = [&](int s, int tgt, bool producer) {
    __syncthreads();
    if (producer && tid == 0) stci(flg(s, bid), tgt);
  };
  auto wait_flags = [&](int s, int base, int count, int tgt) {
    if (wv == 0) {
      const int m = count - 1;
      for (;;) {
        bool ok = true;
        for (int f = lane; f < count; f += 64)
          ok &= (ldci(flg(s, base + ((f + bid) & m))) >= tgt);
        if (__all(ok)) break;
        __builtin_amdgcn_s_sleep(12);
      }
    }
    __syncthreads();
  };
  auto stage_raw = [&](const float* src) {
    const float4* s4 = (const float4*)src;
    float4* d4 = (float4*)s_raw;
    for (int k = tid; k < 1024; k += NT) d4[k] = s4[k];
    __syncthreads();
  };
  // wave-level LN of one 512-vector: dst = LN(xa+xb)*g+b  (write-through)
  auto ln_vec = [&](const float* xa, const float* xb, int lnidx, float* dst) {
    const float* gg = ln_g + (size_t)lnidx * E;
    const float* be = ln_b + (size_t)lnidx * E;
    float v[8]; float sum = 0.f;
#pragma unroll
    for (int j = 0; j < 8; ++j) {
      int d = lane + 64 * j;
      v[j] = xa[d] + xb[d];
      sum += v[j];
    }
    sum = wsum(sum);
    float mean = sum * (1.f / 512.f);
    float d2 = 0.f;
#pragma unroll
    for (int j = 0; j < 8; ++j) { float dd = v[j] - mean; d2 += dd * dd; }
    d2 = wsum(d2);
    float inv = 1.f / sqrtf(d2 * (1.f / 512.f) + 1e-5f);
#pragma unroll
    for (int j = 0; j < 8; ++j) {
      int d = lane + 64 * j;
      stc(&dst[d], (v[j] - mean) * inv * gg[d] + be[d]);
    }
  };
  // prefill proj: 2 rows (bid*2+j) x 96 tokens from panel-staged src
  auto pproj = [&](const float* Wb, const float* biasp, const float* src, float* dst) {
    int j = wv >> 3, tt = wv & 7;
    int r = bid * 2 + j;
    const f4* wp = (const f4*)(Wb + (size_t)r * E);
    f4 w0 = wp[lane], w1 = wp[lane + 64];
    float bias = biasp[r];
    for (int g = 0; g < 12; ++g) {
      stage_raw(src + (size_t)g * 8 * E);
      const f4* x4 = (const f4*)&s_raw[tt * E];
      f4 a = w0 * x4[lane] + w1 * x4[lane + 64];
      float acc = a.x + a.y + a.z + a.w;
      acc = wsum(acc);
      if (lane == 0) stc(&dst[(size_t)(g * 8 + tt) * E + r], acc + bias);
      __syncthreads();
    }
  };

  // ======================= PREFILL (positions 0..11) =======================
  {
    // ---- P0 (id 39): cross K/V over 384 encoder tokens ----
    for (int l = 0; l < NL; ++l) {
      const int rr = (bid >> 2) * 16 + wv;          // 0..1023
      const int sec = rr >> 9, off = rr & 511;
      const f4* wp = (const f4*)(ca_w + ((size_t)l * 1536 + 512 + rr) * E);
      f4 w0 = wp[lane], w1 = wp[lane + 64];
      float bias = ca_b[(size_t)l * 1536 + 512 + rr];
      float* dst = (sec == 0 ? kcross : vcross) + (size_t)l * CROSS_SZ;
      for (int g = 0; g < 12; ++g) {
        int t0 = (bid & 3) * 96 + g * 8;
        stage_raw(enc + (size_t)t0 * E);
        for (int tt = 0; tt < 8; ++tt) {
          const f4* x4 = (const f4*)&s_raw[tt * E];
          f4 a = w0 * x4[lane] + w1 * x4[lane + 64];
          float acc = a.x + a.y + a.z + a.w;
          acc = wsum(acc);
          if (lane == 0) stc(&dst[(size_t)(t0 + tt) * E + off], acc + bias);
        }
        __syncthreads();
      }
    }
    set_flag(39, 1, true);

    for (int l = 0; l < NL; ++l) {
      const int PB = 17 + l * 11;
      float* PL = pre + (size_t)l * PRE_L;
      float* q_l = PL + PQ_OFF;  float* attS_l = PL + PATTS; float* rawS_l = PL + PRAWS;
      float* x1_l = PL + PX1;    float* qc_l = PL + PQC;     float* attC_l = PL + PATTC;
      float* rawC_l = PL + PRAWC; float* x2_l = PL + PX2;    float* y_l = PL + PY;
      float* x3_l = PL + PX3;    float* hb_l = PL + PHB;
      const float* xsrc = (l == 0) ? xpre : (pre + PX3);     // layer-0 x3

      if (l == 1) wait_flags(17 + 10, 0, 128, 1);            // layer-0 LN3
      // ---- P1: QKV (6 rows/block x 96 tokens) ----
      {
        int j = wv >> 1, bg = (wv & 1) * 4;
        int r = bid * 6 + j, sec = r >> 9, off = r & 511;
        f4 w0, w1; float bias = 0.f;
        if (wv < 12) {
          const f4* wp = (const f4*)(sa_w + ((size_t)l * 1536 + r) * E);
          w0 = wp[lane]; w1 = wp[lane + 64];
          bias = sa_b[(size_t)l * 1536 + r];
        }
        for (int g = 0; g < 12; ++g) {
          stage_raw(xsrc + (size_t)g * 8 * E);
          if (wv < 12) {
            for (int tt = bg; tt < bg + 4; ++tt) {
              const f4* x4 = (const f4*)&s_raw[tt * E];
              f4 a = w0 * x4[lane] + w1 * x4[lane + 64];
              float acc = a.x + a.y + a.z + a.w;
              acc = wsum(acc);
              if (lane == 0) {
                int t = g * 8 + tt; acc += bias;
                if (sec == 0) stc(&q_l[(size_t)t * E + off], acc);
                else if (sec == 1) stc(&kself[((size_t)l * LF * B + t) * E + off], acc);
                else stc(&vself[((size_t)l * LF * B + t) * E + off], acc);
              }
            }
          }
          __syncthreads();
        }
      }
      set_flag(PB + 0, 1, true);
      wait_flags(PB + 0, 0, 256, 1);
      // ---- P2: self-attn (768 q-units on blocks 0..47) ----
      if (bid < 48) {
        int u = bid * 16 + wv, qi = u >> 6, rr = u & 63, b = rr >> 3, h = rr & 7;
        int nk = qi + 1;
        float qv = q_l[(size_t)(qi * 8 + b) * E + h * DH + lane];
        float sc = -INFINITY;
        for (int k = 0; k < nk; ++k) {
          float pr = wsum(qv * kself[((size_t)l * LF * B + k * 8 + b) * E + h * DH + lane]);
          if (lane == k) sc = pr * 0.125f;
        }
        float m = wmax(sc);
        float e = (lane < nk) ? expf(sc - m) : 0.f;
        float den = wsum(e);
        float aa = e / den, o = 0.f;
        for (int k = 0; k < nk; ++k) {
          float ak = __shfl(aa, k);
          o = fmaf(ak, vself[((size_t)l * LF * B + k * 8 + b) * E + h * DH + lane], o);
        }
        stc(&attS_l[(size_t)(qi * 8 + b) * E + h * DH + lane], o);
      }
      set_flag(PB + 1, 1, bid < 64);
      wait_flags(PB + 1, 0, 64, 1);
      // ---- P3: self out-proj ----
      pproj(sa_ow + (size_t)l * 512 * E, sa_ob + (size_t)l * 512, attS_l, rawS_l);
      set_flag(PB + 2, 1, true);
      wait_flags(PB + 2, 0, 256, 1);
      // ---- P4: LN1 (token = bid, blocks 0..95) ----
      if (bid < 96 && wv == 0)
        ln_vec(xsrc + (size_t)bid * E, rawS_l + (size_t)bid * E, l * 3 + 0, x1_l + (size_t)bid * E);
      set_flag(PB + 3, 1, bid < 128);
      wait_flags(PB + 3, 0, 128, 1);
      // ---- P5: cross-Q proj ----
      pproj(ca_w + (size_t)l * 1536 * E, ca_b + (size_t)l * 1536, x1_l, qc_l);
      set_flag(PB + 4, 1, true);
      wait_flags(PB + 4, 0, 256, 1);
      wait_flags(39, 0, 256, 1);
      // ---- P6: cross-attn (48 keys) ----
      if (bid < 48) {
        int u = bid * 16 + wv, qi = u >> 6, rr = u & 63, b = rr >> 3, h = rr & 7;
        const float* Kc = kcross + (size_t)l * CROSS_SZ;
        const float* Vc = vcross + (size_t)l * CROSS_SZ;
        float qv = qc_l[(size_t)(qi * 8 + b) * E + h * DH + lane];
        float sc = -INFINITY;
        for (int k = 0; k < S; ++k) {
          float pr = wsum(qv * Kc[(size_t)(k * 8 + b) * E + h * DH + lane]);
          if (lane == k) sc = pr * 0.125f;
        }
        float m = wmax(sc);
        float e = (lane < S) ? expf(sc - m) : 0.f;
        float den = wsum(e);
        float aa = e / den, o = 0.f;
        for (int k = 0; k < S; ++k) {
          float ak = __shfl(aa, k);
          o = fmaf(ak, Vc[(size_t)(k * 8 + b) * E + h * DH + lane], o);
        }
        stc(&attC_l[(size_t)(qi * 8 + b) * E + h * DH + lane], o);
      }
      set_flag(PB + 5, 1, bid < 64);
      wait_flags(PB + 5, 0, 64, 1);
      // ---- P7: cross out-proj ----
      pproj(ca_ow + (size_t)l * 512 * E, ca_ob + (size_t)l * 512, attC_l, rawC_l);
      set_flag(PB + 6, 1, true);
      wait_flags(PB + 6, 0, 256, 1);
      // ---- P8: LN2 ----
      if (bid < 96 && wv == 0)
        ln_vec(x1_l + (size_t)bid * E, rawC_l + (size_t)bid * E, l * 3 + 1, x2_l + (size_t)bid * E);
      set_flag(PB + 7, 1, bid < 128);
      wait_flags(PB + 7, 0, 128, 1);
      // ---- P9: ff1 (relu; 8 rows/block) ----
      {
        int j = wv >> 1, bg = (wv & 1) * 4;
        int r = bid * 8 + j;
        const f4* wp = (const f4*)(ff1_w + ((size_t)l * FF + r) * E);
        f4 w0 = wp[lane], w1 = wp[lane + 64];
        float bias = ff1_b[(size_t)l * FF + r];
        for (int g = 0; g < 12; ++g) {
          stage_raw(x2_l + (size_t)g * 8 * E);
          for (int tt = bg; tt < bg + 4; ++tt) {
            const f4* x4 = (const f4*)&s_raw[tt * E];
            f4 a = w0 * x4[lane] + w1 * x4[lane + 64];
            float acc = a.x + a.y + a.z + a.w;
            acc = wsum(acc);
            if (lane == 0)
              stc(&hb_l[(size_t)(g * 8 + tt) * FF + r], fmaxf(acc + bias, 0.f));
          }
          __syncthreads();
        }
      }
      set_flag(PB + 8, 1, true);
      wait_flags(PB + 8, 0, 256, 1);
      // ---- P10: ff2 (blocks of this layer's half; 4 rows x 96 tokens, K=2048) ----
      if ((bid >> 7) == l) {
        int r0 = (bid & 127) * 4;
        for (int u = wv; u < 384; u += 16) {
          int t = u >> 2, rl = u & 3;
          const f4* h4 = (const f4*)(hb_l + (size_t)t * FF);
          const f4* wp = (const f4*)(ff2_w + ((size_t)l * 512 + r0 + rl) * FF);
          float acc = 0.f;
#pragma unroll
          for (int j = 0; j < 8; ++j) {
            f4 hv = h4[j * 64 + lane];
            f4 w = wp[j * 64 + lane];
            acc += w.x * hv.x + w.y * hv.y + w.z * hv.z + w.w * hv.w;
          }
          acc = wsum(acc);
          if (lane == 0)
            stc(&y_l[(size_t)t * E + r0 + rl], acc + ff2_b[(size_t)l * 512 + r0 + rl]);
        }
      }
      set_flag(PB + 9, 1, (bid >> 7) == l);
      wait_flags(PB + 9, l * 128, 128, 1);
      // ---- P11: LN3 ----
      if (bid < 96 && wv == 0)
        ln_vec(x2_l + (size_t)bid * E, y_l + (size_t)bid * E, l * 3 + 2, x3_l + (size_t)bid * E);
      set_flag(PB + 10, 1, bid < 128);
    }

    // ---- prefill logits (96 tokens x 125 rows/block) + pos-11 partial argmax ----
    wait_flags(17 + 11 + 10, 0, 128, 1);
    {
      float* s_acc = s_w;                       // 128x96 scratch (48 KB)
      const float* x3f = pre + PRE_L + PX3;     // layer-1 x3
      const int grp = lane >> 3, sub = lane & 7;
      const int idx = wv * 8 + grp;
      const bool valid = idx < 125;
      const int r = bid * 125 + idx;
      for (int k = tid; k < 128 * 96; k += NT) s_acc[k] = 0.f;
      __syncthreads();
      for (int half = 0; half < 2; ++half) {
        f4 w8[8];
        if (valid) {
          const f4* wrow = (const f4*)(out_w + (size_t)r * E);
#pragma unroll
          for (int j = 0; j < 8; ++j) w8[j] = wrow[(half * 8 + j) * 8 + sub];
        }
        for (int g = 0; g < 12; ++g) {
          stage_raw(x3f + (size_t)g * 8 * E);
          if (valid) {
            for (int b = 0; b < 8; ++b) {
              const f4* x4 = (const f4*)&s_raw[b * E];
              float a = 0.f;
#pragma unroll
              for (int j = 0; j < 8; ++j) {
                f4 xx = x4[(half * 8 + j) * 8 + sub];
                a += w8[j].x * xx.x + w8[j].y * xx.y + w8[j].z * xx.z + w8[j].w * xx.w;
              }
              a += __shfl_xor(a, 1);
              a += __shfl_xor(a, 2);
              a += __shfl_xor(a, 4);
              if (sub == 0) s_acc[idx * 96 + g * 8 + b] += a;
            }
          }
          __syncthreads();
        }
      }
      if (valid) {
        float bo = out_b[r];
        for (int k = sub; k < 96; k += 8)
          outp[(size_t)k * V + r] = s_acc[idx * 96 + k] + bo;   // host-only reader
      }
      __syncthreads();
      for (int b = 0; b < 8; ++b) {
        float v = (valid && sub == 0) ? s_acc[idx * 96 + 88 + b] + out_b[r] : -INFINITY;
        int ix = (valid && sub == 0) ? r : 0x7fffffff;
#pragma unroll
        for (int off = 1; off < 64; off <<= 1) {
          float ov = __shfl_xor(v, off); int oi = __shfl_xor(ix, off);
          CMB(v, ix, ov, oi);
        }
        if (lane == 0) { s_pv[wv][b] = v; s_pi[wv][b] = ix; }
      }
      __syncthreads();
      if (wv == 0) {
        int b = lane & 7, w2 = lane >> 3;
        float v = s_pv[w2][b]; int ix = s_pi[w2][b];
        float v2 = s_pv[w2 + 8][b]; int ix2 = s_pi[w2 + 8][b];
        CMB(v, ix, v2, ix2);
#pragma unroll
        for (int off = 8; off < 64; off <<= 1) {
          float ov = __shfl_xor(v, off); int oi = __shfl_xor(ix, off);
          CMB(v, ix, ov, oi);
        }
        if (lane < 8) stc8(&amax_pre[(size_t)(bid * 8 + lane) * 2], v, (float)ix);
      }
      __syncthreads();
    }
    set_flag(40, 1, true);
  }

  // ---- load decode weight slices into LDS (s_w scratch now free) ----
  {
    auto cprow = [&](const float* src, int dstf) {
      f4* d = (f4*)&s_w[dstf]; const f4* s = (const f4*)src;
      for (int k = tid; k < 128; k += NT) d[k] = s[k];
    };
    for (int l = 0; l < NL; ++l) {
      for (int j = 0; j < 6; ++j)
        cprow(sa_w + ((size_t)l * 1536 + bid * 6 + j) * E, B_QKV + (l * 6 + j) * 512);
      for (int j = 0; j < 2; ++j) {
        cprow(sa_ow + ((size_t)l * 512 + bid * 2 + j) * E, B_OW + (l * 2 + j) * 512);
        cprow(ca_w + ((size_t)l * 1536 + bid * 2 + j) * E, B_CQ + (l * 2 + j) * 512);
        cprow(ca_ow + ((size_t)l * 512 + bid * 2 + j) * E, B_COW + (l * 2 + j) * 512);
      }
      for (int j = 0; j < 8; ++j)
        cprow(ff1_w + ((size_t)l * FF + bid * 8 + j) * E, B_FF1 + (l * 8 + j) * 512);
    }
    const int lf2 = bid >> 7;
    for (int j = 0; j < 4; ++j) {
      f4* d = (f4*)&s_w[B_FF2 + j * 2048];
      const f4* s = (const f4*)(ff2_w + ((size_t)lf2 * 512 + (bid & 127) * 4 + j) * FF);
      for (int k = tid; k < 512; k += NT) d[k] = s[k];
    }
    __syncthreads();
  }

  // ---- decode stage helpers (r10, proven) ----
  auto lnstage = [&](int lnidx) {
    if (wv < 8) {
      const float* gg = ln_g + (size_t)lnidx * E;
      const float* be = ln_b + (size_t)lnidx * E;
      float v[8]; float sum = 0.f;
#pragma unroll
      for (int j = 0; j < 8; ++j) {
        int d = lane + 64 * j;
        v[j] = s_x[wv * E + d] + s_raw[wv * E + d];
        sum += v[j];
      }
      sum = wsum(sum);
      float mean = sum * (1.f / 512.f);
      float d2 = 0.f;
#pragma unroll
      for (int j = 0; j < 8; ++j) { float dd = v[j] - mean; d2 += dd * dd; }
      d2 = wsum(d2);
      float inv = 1.f / sqrtf(d2 * (1.f / 512.f) + 1e-5f);
#pragma unroll
      for (int j = 0; j < 8; ++j) {
        int d = lane + 64 * j;
        s_x[wv * E + d] = (v[j] - mean) * inv * gg[d] + be[d];
      }
    }
    __syncthreads();
  };
  auto proj16 = [&](int wbase, const float* srcLDS, const float* biasp, float* dst) {
    int j = wv & 1, b = wv >> 1;
    int r = bid * 2 + j;
    const f4* wp = (const f4*)&s_w[wbase + j * 512];
    f4 w0 = wp[lane], w1 = wp[lane + 64];
    const f4* x4 = (const f4*)(srcLDS + b * E);
    f4 a = w0 * x4[lane] + w1 * x4[lane + 64];
    float acc = a.x + a.y + a.z + a.w;
    acc = wsum(acc);
    if (lane == 0) stc(&dst[b * E + r], acc + biasp[r]);
  };
  auto attn_stage = [&](const float* qsrc, const float* Kbase, const float* Vbase,
                        int nk, float* attdst) {
    const int b = bid >> 3, h = bid & 7;
    if (wv == 0) {
      s_q2[lane] = qsrc[b * E + h * DH + lane];
      float sc = -INFINITY;
      if (lane < nk) {
        const f4* Kr = (const f4*)(Kbase + ((size_t)lane * B + b) * E + h * DH);
        const f4* Qp = (const f4*)s_q2;
        float a0 = 0.f;
#pragma unroll
        for (int u = 0; u < 16; ++u) {
          f4 kv = Kr[u], qq = Qp[u];
          a0 += kv.x * qq.x + kv.y * qq.y + kv.z * qq.z + kv.w * qq.w;
        }
        sc = a0 * 0.125f;
      }
      float m = wmax(sc);
      float e = (lane < nk) ? expf(sc - m) : 0.f;
      float den = wsum(e);
      s_attw[lane] = e / den;
    }
    __syncthreads();
    if (wv < 4) {
      float o = 0.f;
      for (int k = wv; k < nk; k += 4)
        o = fmaf(s_attw[k], Vbase[((size_t)k * B + b) * E + h * DH + lane], o);
      s_part[wv][lane] = o;
    }
    __syncthreads();
    if (wv == 0)
      stc(&attdst[b * E + h * DH + lane],
          s_part[0][lane] + s_part[1][lane] + s_part[2][lane] + s_part[3][lane]);
  };

  // ---- 23 autoregressive steps (r10, proven) ----
  for (int i = 0; i < MAXLEN - 1; ++i) {
    const int p = INIT + i;
    const int tgt = i + 1;
    float* amax_o = slot(i, 0);

    if (i == 0) wait_flags(40, 0, 256, 1);
    else        wait_flags(16, 0, 256, i);
    {
      int bw = wv & 7;
      float v = -INFINITY; int ix = 0x7fffffff;
      const float2* ap = (i == 0) ? (const float2*)amax_pre : (const float2*)slot(i - 1, 0);
#pragma unroll
      for (int t = 0; t < 4; ++t) {
        int e = lane * 4 + t;
        float2 pr = ap[e * 8 + bw];
        CMB(v, ix, pr.x, (int)pr.y);
      }
#pragma unroll
      for (int off = 1; off < 64; off <<= 1) {
        float ov = __shfl_xor(v, off); int oi = __shfl_xor(ix, off);
        CMB(v, ix, ov, oi);
      }
      if (lane == 0 && wv < 8) s_tok[bw] = ix;
      __syncthreads();
      int b = tid >> 7, d0 = (tid & 127) * 4;
      int tok = s_tok[b];
      float4 ev = *(const float4*)(emb + (size_t)tok * E + d0);
      s_x[b * E + d0]     = ev.x;
      s_x[b * E + d0 + 1] = ev.y + 1.0f;
      s_x[b * E + d0 + 2] = ev.z;
      s_x[b * E + d0 + 3] = ev.w + 1.0f;
      __syncthreads();
    }

    for (int l = 0; l < NL; ++l) {
      const int sb = l * 8;
      float* Lb    = slot(i, 1 + l * 11);
      float* q_s   = Lb;
      float* att_s = Lb + 4096;
      float* raw_s = Lb + 8192;
      float* q_c   = Lb + 12288;
      float* att_c = Lb + 16384;
      float* raw_c = Lb + 20480;
      float* hb    = Lb + 24576;
      float* yb    = Lb + 40960;

      if (wv < 12) {
        int j = wv >> 1, bg = (wv & 1) * 4;
        int r = bid * 6 + j, sec = r >> 9, off = r & 511;
        const f4* wp = (const f4*)&s_w[B_QKV + (l * 6 + j) * 512];
        f4 w0 = wp[lane], w1 = wp[lane + 64];
        float bias = sa_b[(size_t)l * 1536 + r];
        for (int b = bg; b < bg + 4; ++b) {
          const f4* x4 = (const f4*)&s_x[b * E];
          f4 a = w0 * x4[lane] + w1 * x4[lane + 64];
          float acc = a.x + a.y + a.z + a.w;
          acc = wsum(acc);
          if (lane == 0) {
            acc += bias;
            if (sec == 0) stc(&q_s[b * E + off], acc);
            else if (sec == 1) stc(&kself[((size_t)(l * LF + p) * B + b) * E + off], acc);
            else stc(&vself[((size_t)(l * LF + p) * B + b) * E + off], acc);
          }
        }
      }
      set_flag(sb + 0, tgt, true);
      wait_flags(sb + 0, 0, 256, tgt);
      if (bid < 64)
        attn_stage(q_s, kself + (size_t)l * LF * B * E, vself + (size_t)l * LF * B * E,
                   p + 1, att_s);
      set_flag(sb + 1, tgt, bid < 64);
      wait_flags(sb + 1, 0, 64, tgt);
      stage_raw(att_s);
      proj16(B_OW + l * 1024, s_raw, sa_ob + (size_t)l * E, raw_s);
      set_flag(sb + 2, tgt, true);
      wait_flags(sb + 2, 0, 256, tgt);
      stage_raw(raw_s);
      lnstage(l * 3 + 0);
      proj16(B_CQ + l * 1024, s_x, ca_b + (size_t)l * 3 * E, q_c);
      set_flag(sb + 3, tgt, true);
      wait_flags(sb + 3, 0, 256, tgt);
      if (bid < 64)
        attn_stage(q_c, kcross + (size_t)l * CROSS_SZ, vcross + (size_t)l * CROSS_SZ,
                   S, att_c);
      set_flag(sb + 4, tgt, bid < 64);
      wait_flags(sb + 4, 0, 64, tgt);
      stage_raw(att_c);
      proj16(B_COW + l * 1024, s_raw, ca_ob + (size_t)l * E, raw_c);
      set_flag(sb + 5, tgt, true);
      wait_flags(sb + 5, 0, 256, tgt);
      stage_raw(raw_c);
      lnstage(l * 3 + 1);
      {
        int j = wv >> 1, bg = (wv & 1) * 4;
        int r = bid * 8 + j;
        const f4* wp = (const f4*)&s_w[B_FF1 + (l * 8 + j) * 512];
        f4 w0 = wp[lane], w1 = wp[lane + 64];
        float bias = ff1_b[(size_t)l * FF + r];
        for (int b = bg; b < bg + 4; ++b) {
          const f4* x4 = (const f4*)&s_x[b * E];
          f4 a = w0 * x4[lane] + w1 * x4[lane + 64];
          float acc = a.x + a.y + a.z + a.w;
          acc = wsum(acc);
          if (lane == 0) stc(&hb[b * FF + r], fmaxf(acc + bias, 0.f));
        }
      }
      set_flag(sb + 6, tgt, true);
      wait_flags(sb + 6, 0, 256, tgt);
      if ((bid >> 7) == l) {
        int b = wv >> 1, j0 = (wv & 1) * 2;
        int r0 = (bid & 127) * 4;
        const f4* h4 = (const f4*)(hb + b * FF);
        f4 hv[8];
#pragma unroll
        for (int j = 0; j < 8; ++j) hv[j] = h4[j * 64 + lane];
#pragma unroll
        for (int jr = 0; jr < 2; ++jr) {
          int rl = j0 + jr;
          const f4* wp = (const f4*)&s_w[B_FF2 + rl * 2048];
          float acc = 0.f;
#pragma unroll
          for (int j = 0; j < 8; ++j) {
            f4 w = wp[j * 64 + lane];
            acc += w.x * hv[j].x + w.y * hv[j].y + w.z * hv[j].z + w.w * hv[j].w;
          }
          acc = wsum(acc);
          if (lane == 0)
            stc(&yb[b * E + r0 + rl], acc + ff2_b[(size_t)l * 512 + r0 + rl]);
        }
      }
      set_flag(sb + 7, tgt, (bid >> 7) == l);
      wait_flags(sb + 7, l * 128, 128, tgt);
      stage_raw(yb);
      lnstage(l * 3 + 2);
    }

    {
      const int grp = lane >> 3, sub = lane & 7;
      const int idx = wv * 8 + grp;
      const bool valid = idx < 125;
      const int r = bid * 125 + idx;
      float acc[8] = {0, 0, 0, 0, 0, 0, 0, 0};
      if (valid) {
        const f4* wrow = (const f4*)(out_w + (size_t)r * E);
#pragma unroll
        for (int half = 0; half < 2; ++half) {
          f4 w8[8];
#pragma unroll
          for (int j = 0; j < 8; ++j) w8[j] = wrow[(half * 8 + j) * 8 + sub];
#pragma unroll
          for (int b = 0; b < 8; ++b) {
            const f4* x4 = (const f4*)&s_x[b * E];
            float a = 0.f;
#pragma unroll
            for (int j = 0; j < 8; ++j) {
              f4 xx = x4[(half * 8 + j) * 8 + sub];
              a += w8[j].x * xx.x + w8[j].y * xx.y + w8[j].z * xx.z + w8[j].w * xx.w;
            }
            acc[b] += a;
          }
        }
#pragma unroll
        for (int b = 0; b < 8; ++b) {
          acc[b] += __shfl_xor(acc[b], 1);
          acc[b] += __shfl_xor(acc[b], 2);
          acc[b] += __shfl_xor(acc[b], 4);
        }
        if (sub == 0) {
          float bo = out_b[r];
#pragma unroll
          for (int b = 0; b < 8; ++b) {
            acc[b] += bo;
            outp[((size_t)p * B + b) * V + r] = acc[b];
          }
        }
      }
#pragma unroll
      for (int b = 0; b < 8; ++b) {
        float v = (valid && sub == 0) ? acc[b] : -INFINITY;
        int ix = (valid && sub == 0) ? r : 0x7fffffff;
#pragma unroll
        for (int off = 1; off < 64; off <<= 1) {
          float ov = __shfl_xor(v, off); int oi = __shfl_xor(ix, off);
          CMB(v, ix, ov, oi);
        }
        if (lane == 0) { s_pv[wv][b] = v; s_pi[wv][b] = ix; }
      }
      __syncthreads();
      if (wv == 0) {
        int b = lane & 7, w2 = lane >> 3;
        float v = s_pv[w2][b]; int ix = s_pi[w2][b];
        float v2 = s_pv[w2 + 8][b]; int ix2 = s_pi[w2 + 8][b];
        CMB(v, ix, v2, ix2);
#pragma unroll
        for (int off = 8; off < 64; off <<= 1) {
          float ov = __shfl_xor(v, off); int oi = __shfl_xor(ix, off);
          CMB(v, ix, ov, oi);
        }
        if (lane < 8) stc8(&amax_o[(size_t)(bid * 8 + lane) * 2], v, (float)ix);
      }
    }
    set_flag(16, tgt, true);
  }
}

extern "C" void kernel_launch(void* const* d_in, const int* in_sizes, int n_in,
                              void* d_out, int out_size, void* d_ws, size_t ws_size,
                              hipStream_t stream) {
  const float* enc       = (const float*)d_in[0];
  const int*   transform = (const int*)d_in[1];
  const float* emb       = (const float*)d_in[3];
  const float* sa_w  = (const float*)d_in[4];
  const float* sa_b  = (const float*)d_in[5];
  const float* sa_ow = (const float*)d_in[6];
  const float* sa_ob = (const float*)d_in[7];
  const float* ca_w  = (const float*)d_in[8];
  const float* ca_b  = (const float*)d_in[9];
  const float* ca_ow = (const float*)d_in[10];
  const float* ca_ob = (const float*)d_in[11];
  const float* ff1_w = (const float*)d_in[12];
  const float* ff1_b = (const float*)d_in[13];
  const float* ff2_w = (const float*)d_in[14];
  const float* ff2_b = (const float*)d_in[15];
  const float* ln_g  = (const float*)d_in[16];
  const float* ln_b  = (const float*)d_in[17];
  const float* out_w = (const float*)d_in[18];
  const float* out_b = (const float*)d_in[19];
  float* out = (float*)d_out;

  // workspace layout (floats)
  const size_t SELF_SZ  = (size_t)LF * B * E;
  const size_t CROSS_SZ = (size_t)S * B * E;
  const size_t ARENA_SZ = (size_t)(MAXLEN - 1) * SLOTS_PER_STEP * 4096;
  const size_t FLAG_SZ  = (size_t)NSTAGE * 256 * 16;   // ints
  float* ws     = (float*)d_ws;
  float* xpre   = ws;                                  // [96,512]
  float* kself  = xpre + 96 * E;
  float* vself  = kself + NL * SELF_SZ;
  float* kcross = vself + NL * SELF_SZ;
  float* vcross = kcross + NL * CROSS_SZ;
  float* arena  = vcross + NL * CROSS_SZ;
  float* pre    = arena + ARENA_SZ;                    // [2, PRE_L]
  float* amaxp  = pre + (size_t)NL * PRE_L;            // [256,8,2]
  int*   bar    = (int*)(amaxp + 4096);

  hipMemsetAsync(bar, 0, FLAG_SZ * 4, stream);

  // initial token embeddings (positions 0..11)
  embed_init_k<<<96, 128, 0, stream>>>(transform, emb, xpre);

  // everything else: one persistent kernel (prefill + 23 decode steps)
  decode_persist_k<<<NB, NT, 0, stream>>>(
      enc, emb, sa_w, sa_b, sa_ow, sa_ob, ca_w, ca_b, ca_ow, ca_ob,
      ff1_w, ff1_b, ff2_w, ff2_b, ln_g, ln_b, out_w, out_b,
      xpre, pre, amaxp, kself, vself, kcross, vcross, arena, out, bar);
}